// Round 9
// baseline (884.683 us; speedup 1.0000x reference)
//
#include <hip/hip_runtime.h>
#include <hip/hip_fp16.h>

typedef _Float16 f16;
typedef _Float16 f16x4 __attribute__((ext_vector_type(4)));
typedef _Float16 f16x8 __attribute__((ext_vector_type(8)));
typedef float f32x4 __attribute__((ext_vector_type(4)));
typedef float f32x16 __attribute__((ext_vector_type(16)));
typedef unsigned int u32;
typedef u32 u32x4 __attribute__((ext_vector_type(4)));

static constexpr int CB = 8;      // batch
static constexpr int CC = 256;    // channels = Co
static constexpr int CN = 4096;   // tokens = H*W
static constexpr size_t SZ = (size_t)CB * CN * CC;   // elems of one [B,N,256] slab

#define MFMA(a, b, c)   __builtin_amdgcn_mfma_f32_16x16x32_f16((a), (b), (c), 0, 0, 0)
#define MFMA32(a, b, c) __builtin_amdgcn_mfma_f32_32x32x16_f16((a), (b), (c), 0, 0, 0)

__device__ __forceinline__ void gll16(const void* g, void* l) {
  __builtin_amdgcn_global_load_lds(
      (const __attribute__((address_space(1))) unsigned int*)g,
      (__attribute__((address_space(3))) unsigned int*)l, 16, 0, 0);
}

// swap a's lanes 32-63 with b's lanes 0-31 (CDNA4 cross-half exchange)
__device__ __forceinline__ void plswap(u32& a, u32& b) {
  asm volatile("v_permlane32_swap_b32 %0, %1" : "+v"(a), "+v"(b));
}

__device__ __forceinline__ u32 pk(float lo, float hi) {
  auto h = __builtin_amdgcn_cvt_pkrtz(lo, hi);   // __fp16 ext_vector_type(2)
  return __builtin_bit_cast(u32, h);
}

__global__ __launch_bounds__(256) void prep_weights(const float* __restrict__ wq,
    const float* __restrict__ wk, const float* __restrict__ wv,
    const float* __restrict__ wo, f16* __restrict__ W) {
  int i = blockIdx.x * 256 + threadIdx.x;
  W[i]          = (f16)wq[i];
  W[65536 + i]  = (f16)wk[i];
  W[131072 + i] = (f16)wv[i];
  W[196608 + i] = (f16)wo[i];
}

// x [B,C,N] fp32  ->  Q,K [B,N,256] f16 ; V^T [B,256,N] f16   (unchanged, verified)
__global__ __launch_bounds__(256) void qkv_kernel(const float* __restrict__ x,
    const f16* __restrict__ Wq, const f16* __restrict__ Wk, const f16* __restrict__ Wv,
    const float* __restrict__ bq, const float* __restrict__ bk, const float* __restrict__ bv,
    f16* __restrict__ Q, f16* __restrict__ K, f16* __restrict__ Vt) {
  __shared__ f16 xf[64][264];
  const int b  = blockIdx.x >> 6;
  const int n0 = (blockIdx.x & 63) << 6;
  const int t  = threadIdx.x;
  const float* xb = x + (size_t)b * CC * CN;
  {
    int c = t >> 4;
    const int nn = (t & 15) << 2;
    #pragma unroll
    for (int pass = 0; pass < 16; ++pass, c += 16) {
      const float4 v = *(const float4*)(xb + (size_t)c * CN + n0 + nn);
      xf[nn + 0][c] = (f16)v.x;
      xf[nn + 1][c] = (f16)v.y;
      xf[nn + 2][c] = (f16)v.z;
      xf[nn + 3][c] = (f16)v.w;
    }
  }
  __syncthreads();
  const int w = t >> 6, l = t & 63, lr = l & 15, lh = l >> 4;

  f16x8 xff[8];
  #pragma unroll
  for (int kk = 0; kk < 8; ++kk)
    xff[kk] = *(const f16x8*)&xf[w * 16 + lr][kk * 32 + lh * 8];

  const size_t qkrow = ((size_t)b * CN + n0 + w * 16 + lr) * CC;

  #pragma unroll 1
  for (int mat = 0; mat < 2; ++mat) {
    const f16* W = mat ? Wk : Wq;
    const float* bias = mat ? bk : bq;
    f16* dst = mat ? K : Q;
    f32x4 acc[16];
    #pragma unroll
    for (int m = 0; m < 16; ++m) acc[m] = f32x4{0.f, 0.f, 0.f, 0.f};
    #pragma unroll
    for (int kk = 0; kk < 8; ++kk) {
      #pragma unroll
      for (int m = 0; m < 16; ++m) {
        f16x8 af = *(const f16x8*)&W[(size_t)(m * 16 + lr) * CC + kk * 32 + lh * 8];
        acc[m] = MFMA(af, xff[kk], acc[m]);
      }
    }
    #pragma unroll
    for (int m = 0; m < 16; ++m) {
      const int o = m * 16 + lh * 4;
      const float4 bs = *(const float4*)&bias[o];
      f16x4 hv;
      hv[0] = (f16)(acc[m][0] + bs.x);
      hv[1] = (f16)(acc[m][1] + bs.y);
      hv[2] = (f16)(acc[m][2] + bs.z);
      hv[3] = (f16)(acc[m][3] + bs.w);
      *(f16x4*)&dst[qkrow + o] = hv;
    }
  }
  {
    f32x4 acc[16];
    #pragma unroll
    for (int m = 0; m < 16; ++m) acc[m] = f32x4{0.f, 0.f, 0.f, 0.f};
    #pragma unroll
    for (int kk = 0; kk < 8; ++kk) {
      #pragma unroll
      for (int m = 0; m < 16; ++m) {
        f16x8 bf = *(const f16x8*)&Wv[(size_t)(m * 16 + lr) * CC + kk * 32 + lh * 8];
        acc[m] = MFMA(xff[kk], bf, acc[m]);
      }
    }
    #pragma unroll
    for (int m = 0; m < 16; ++m) {
      const int o = m * 16 + lr;
      const float bvs = bv[o];
      f16x4 hv;
      #pragma unroll
      for (int j = 0; j < 4; ++j) hv[j] = (f16)(acc[m][j] + bvs);
      *(f16x4*)&Vt[((size_t)b * CC + o) * CN + n0 + w * 16 + lh * 4] = hv;
    }
  }
}

// flash attention v8: kv-half split (grid 1024) + 48.5KB LDS (K dbuf + V single)
// -> 3 blocks/CU, 12 waves/CU. Per-iter: stageV(own) | stageK(next) | QK | SM |
// vmcnt(0) | PV | barrier. Partials (normalized O + m,l) combined in oproj.
// Q,K [B,N,256], V^T [B,256,N] -> Op[2][B,N,256] f16, ML[2][B,N] float2
__global__ __launch_bounds__(256, 3) void attn_kernel(const f16* __restrict__ Q,
    const f16* __restrict__ K, const f16* __restrict__ Vt,
    f16* __restrict__ Op, float2* __restrict__ ML) {
  // SMEM (bytes):
  //   [0, 32768):     K frames: buf*16384 + ks*1024, ks=0..15. Frag-linear (+16*l).
  //   [32768, 49152): V frames (single buffer): 32768 + f*1024, f=0..15.
  //   [49152, 49664): per-wave alpha floats: w*128
  __shared__ __align__(16) char SMEM[49664];

  const int bid = blockIdx.x;
  const int lb = ((bid & 7) << 7) | (bid >> 3);   // XCD swizzle: batch -> XCD (1024 = 8x128)
  const int b   = lb >> 7;
  const int rr  = lb & 127;
  const int kvh = rr & 1;                         // kv-half
  const int q0  = (rr >> 1) << 6;                 // 64 q-rows per block
  const int t  = threadIdx.x;
  const int w  = t >> 6, l = t & 63, ln = l & 31, lh = l >> 5;
  const int g  = w >> 1, hv = w & 1;              // q-group, o-half

  const f16* Qb = Q  + (size_t)b * CN * CC;
  const f16* Kb = K  + (size_t)b * CN * CC;
  const f16* Vb = Vt + (size_t)b * CC * CN;

  float* const ALf = (float*)(SMEM + 49152 + w * 128);

  // K staging (double-buffered): wave w stages frames 4w..4w+3 (cross-wave reads,
  // made visible by this iter's vmcnt(0)+barrier before next iter's QK)
  auto stageK = [&](int buf, int kv0) {
    const f16* ksrc = Kb + (size_t)(kv0 + ln) * CC + (w * 4) * 16 + 8 * lh;
    #pragma unroll
    for (int j = 0; j < 4; ++j)
      gll16(ksrc + j * 16, SMEM + (buf << 14) + ((w * 4 + j) << 10));
  };
  // V staging (single buffer): each wave stages the 8 frames of ITS OWN o-half.
  // The hv-partner wave writes identical data to the same frames (benign).
  auto stageV = [&](int kv0) {
    #pragma unroll
    for (int j = 0; j < 8; ++j) {
      const int f = 8 * hv + j;
      const f16* vsrc = Vb + (size_t)((f >> 1) * 32 + ln) * CN + kv0 + (f & 1) * 16 + 8 * lh;
      gll16(vsrc, SMEM + 32768 + (f << 10));
    }
  };

  // Q fragments in registers: B-operand of swapped QK^T (lane: q=ln, c=16ks+8lh+e)
  const int qrow = q0 + 32 * g + ln;
  f16x8 qf[16];
  #pragma unroll
  for (int ks = 0; ks < 16; ++ks)
    qf[ks] = *(const f16x8*)(Qb + (size_t)qrow * CC + ks * 16 + 8 * lh);

  f32x16 oacc[4];
  #pragma unroll
  for (int ot = 0; ot < 4; ++ot)
    #pragma unroll
    for (int i = 0; i < 16; ++i) oacc[ot][i] = 0.0f;
  float mrun = -3e38f, lrun = 0.0f;

  const int kvb = kvh << 11;                      // this block's 2048-kv half
  int buf = 0;
  stageK(0, kvb);
  __syncthreads();                                // drains K(0) for all waves

  #pragma unroll 1
  for (int it = 0; it < 64; ++it) {
    stageV(kvb + it * 32);                        // V(it): safe, PV(it-1) done at barrier
    if (it < 63) stageK(buf ^ 1, kvb + (it + 1) * 32);

    // swapped QK^T: S^T[kv][q]; A=K frag (lane: kv=ln, c=16ks+8lh+e), B=Q frag.
    f32x16 s, s1;
    #pragma unroll
    for (int i = 0; i < 16; ++i) { s[i] = 0.0f; s1[i] = 0.0f; }
    __builtin_amdgcn_s_setprio(1);
    #pragma unroll
    for (int ks = 0; ks < 8; ++ks) {
      const f16x8 kf0 = *(const f16x8*)(SMEM + (buf << 14) + (ks << 10) + l * 16);
      s  = MFMA32(kf0, qf[ks], s);
      const f16x8 kf1 = *(const f16x8*)(SMEM + (buf << 14) + ((ks + 8) << 10) + l * 16);
      s1 = MFMA32(kf1, qf[ks + 8], s1);
    }
    __builtin_amdgcn_s_setprio(0);
    #pragma unroll
    for (int i = 0; i < 16; ++i) s[i] += s1[i];

    // online softmax: lane owns q=ln; 16 kv in-lane, partner (l^32) has other 16.
    float mx8[8], mx4[4];
    #pragma unroll
    for (int i = 0; i < 8; ++i) mx8[i] = fmaxf(s[2 * i], s[2 * i + 1]);
    #pragma unroll
    for (int i = 0; i < 4; ++i) mx4[i] = fmaxf(mx8[2 * i], mx8[2 * i + 1]);
    float pmax = fmaxf(fmaxf(mx4[0], mx4[1]), fmaxf(mx4[2], mx4[3]));
    pmax = fmaxf(pmax, __shfl_xor(pmax, 32));
    const bool need = !__all(pmax - mrun <= 8.0f);      // defer-max (T13)
    const float mnew = need ? fmaxf(mrun, pmax) : mrun;
    float p[16];
    #pragma unroll
    for (int r = 0; r < 16; ++r) p[r] = __expf(s[r] - mnew);  // native v_exp_f32
    float sm8[8], sm4[4];
    #pragma unroll
    for (int i = 0; i < 8; ++i) sm8[i] = p[2 * i] + p[2 * i + 1];
    #pragma unroll
    for (int i = 0; i < 4; ++i) sm4[i] = sm8[2 * i] + sm8[2 * i + 1];
    float psum = (sm4[0] + sm4[1]) + (sm4[2] + sm4[3]);
    psum += __shfl_xor(psum, 32);
    if (need) {                                          // rare rescale path
      const float alpha = __expf(mrun - mnew);
      lrun = lrun * alpha + psum;
      mrun = mnew;
      if (l < 32) ALf[ln] = alpha;                       // lanes l, l^32 agree
      #pragma unroll
      for (int r = 0; r < 16; ++r) {
        const float fr = ALf[(r & 3) + 8 * (r >> 2) + 4 * lh];  // alpha of q(r)
        #pragma unroll
        for (int ot = 0; ot < 4; ++ot) oacc[ot][r] *= fr;
      }
    } else {
      lrun += psum;
    }

    // in-register P relayout: pack f32 pairs -> f16x2 words, cross-half swap.
    u32 pw[8];
    #pragma unroll
    for (int i = 0; i < 8; ++i) pw[i] = pk(p[2 * i], p[2 * i + 1]);
    plswap(pw[0], pw[2]); plswap(pw[1], pw[3]);          // kv 0..15
    plswap(pw[4], pw[6]); plswap(pw[5], pw[7]);          // kv 16..31
    const f16x8 pa0 = __builtin_bit_cast(f16x8, u32x4{pw[0], pw[1], pw[2], pw[3]});
    const f16x8 pa1 = __builtin_bit_cast(f16x8, u32x4{pw[4], pw[5], pw[6], pw[7]});

    // drain own V(it) (and own K(it+1), issued ~400+ cyc ago) before PV reads
    asm volatile("s_waitcnt vmcnt(0)" ::: "memory");
    __builtin_amdgcn_sched_barrier(0);

    // PV: D[q][o] += P x V; B=V frag (lane: o=ln, kv=8lh+e); own o-half frames
    __builtin_amdgcn_s_setprio(1);
    #pragma unroll
    for (int ot = 0; ot < 4; ++ot) {
      const int f0 = 8 * hv + 2 * ot;
      const f16x8 v0 = *(const f16x8*)(SMEM + 32768 + (f0 << 10) + l * 16);
      oacc[ot] = MFMA32(pa0, v0, oacc[ot]);
      const f16x8 v1 = *(const f16x8*)(SMEM + 32768 + ((f0 + 1) << 10) + l * 16);
      oacc[ot] = MFMA32(pa1, v1, oacc[ot]);
    }
    __builtin_amdgcn_s_setprio(0);
    __syncthreads();                              // K(it+1)/V visible; Vbuf reusable
    buf ^= 1;
  }

  // epilogue: store normalized partial O-half + (m,l) per q-row
  if (l < 32) ALf[ln] = 1.0f / lrun;
  f16* Ob = Op + (size_t)kvh * SZ + ((size_t)b * CN + q0 + 32 * g) * CC + 128 * hv;
  #pragma unroll
  for (int r = 0; r < 16; ++r) {
    const int q = (r & 3) + 8 * (r >> 2) + 4 * lh;
    const float inv = ALf[q];
    #pragma unroll
    for (int ot = 0; ot < 4; ++ot)
      Ob[(size_t)q * CC + ot * 32 + ln] = (f16)(oacc[ot][r] * inv);
  }
  if (hv == 0 && l < 32)
    ML[((size_t)kvh * CB + b) * CN + q0 + 32 * g + ln] = float2{mrun, lrun};
}

// out[b,c,n] = sum_o (combine of the two kv-half partials)[n,o] * Wo[c,o] + bo[c]
__global__ __launch_bounds__(256) void oproj_kernel(const f16* __restrict__ Op,
    const float2* __restrict__ ML, const f16* __restrict__ Wo,
    const float* __restrict__ bo, float* __restrict__ out) {
  const int b  = blockIdx.x >> 6;
  const int n0 = (blockIdx.x & 63) << 6;
  const int t  = threadIdx.x;
  const int w = t >> 6, l = t & 63, lr = l & 15, lh = l >> 4;
  const size_t row = (size_t)b * CN + n0 + w * 16 + lr;
  // exact softmax merge of the two kv-halves
  const float2 ml0 = ML[row];
  const float2 ml1 = ML[(size_t)CB * CN + row];
  const float mm = fmaxf(ml0.x, ml1.x);
  const float w0 = __expf(ml0.x - mm) * ml0.y;
  const float w1 = __expf(ml1.x - mm) * ml1.y;
  const float inv = 1.0f / (w0 + w1);
  const f16 c0 = (f16)(w0 * inv), c1 = (f16)(w1 * inv);
  const f16* orow0 = Op + row * CC;
  const f16* orow1 = Op + SZ + row * CC;

  f32x4 acc[16];
  #pragma unroll
  for (int m = 0; m < 16; ++m) acc[m] = f32x4{0.f, 0.f, 0.f, 0.f};
  #pragma unroll
  for (int kk = 0; kk < 8; ++kk) {
    const f16x8 b0 = *(const f16x8*)&orow0[kk * 32 + lh * 8];
    const f16x8 b1 = *(const f16x8*)&orow1[kk * 32 + lh * 8];
    const f16x8 bf = b0 * c0 + b1 * c1;
    #pragma unroll
    for (int m = 0; m < 16; ++m) {
      f16x8 af = *(const f16x8*)&Wo[(size_t)(m * 16 + lr) * CC + kk * 32 + lh * 8];
      acc[m] = MFMA(af, bf, acc[m]);
    }
  }
  #pragma unroll
  for (int m = 0; m < 16; ++m) {
    const int c = m * 16 + lh * 4;
    const float4 bv4 = *(const float4*)&bo[c];
    const size_t base = ((size_t)b * CC + c) * CN + n0 + w * 16 + lr;
    out[base + 0 * (size_t)CN] = acc[m][0] + bv4.x;
    out[base + 1 * (size_t)CN] = acc[m][1] + bv4.y;
    out[base + 2 * (size_t)CN] = acc[m][2] + bv4.z;
    out[base + 3 * (size_t)CN] = acc[m][3] + bv4.w;
  }
}

extern "C" void kernel_launch(void* const* d_in, const int* in_sizes, int n_in,
                              void* d_out, int out_size, void* d_ws, size_t ws_size,
                              hipStream_t stream) {
  const float* x  = (const float*)d_in[0];
  const float* wq = (const float*)d_in[1];
  const float* bq = (const float*)d_in[2];
  const float* wk = (const float*)d_in[3];
  const float* bk = (const float*)d_in[4];
  const float* wv = (const float*)d_in[5];
  const float* bv = (const float*)d_in[6];
  const float* wo = (const float*)d_in[7];
  const float* bo = (const float*)d_in[8];

  f16* W  = (f16*)d_ws;                     // 4 x 65536 f16 weights
  f16* Qd = W + 262144;                     // [B,N,256]
  f16* Kd = Qd + SZ;                        // [B,N,256]
  f16* Vt = Kd + SZ;                        // [B,256,N]
  f16* Od = Vt + SZ;                        // Op: [2][B,N,256] partials
  float2* MLd = (float2*)(Od + 2 * SZ);     // [2][B,N] (m,l)

  prep_weights<<<256, 256, 0, stream>>>(wq, wk, wv, wo, W);
  qkv_kernel<<<512, 256, 0, stream>>>(x, W, W + 65536, W + 131072, bq, bk, bv, Qd, Kd, Vt);
  attn_kernel<<<1024, 256, 0, stream>>>(Qd, Kd, Vt, Od, MLd);
  oproj_kernel<<<512, 256, 0, stream>>>(Od, MLd, W + 196608, bo, (float*)d_out);
}

// Round 10
// 757.542 us; speedup vs baseline: 1.1678x; 1.1678x over previous
//
#include <hip/hip_runtime.h>
#include <hip/hip_fp16.h>

typedef _Float16 f16;
typedef _Float16 f16x4 __attribute__((ext_vector_type(4)));
typedef _Float16 f16x8 __attribute__((ext_vector_type(8)));
typedef float f32x4 __attribute__((ext_vector_type(4)));
typedef float f32x16 __attribute__((ext_vector_type(16)));
typedef unsigned int u32;
typedef u32 u32x4 __attribute__((ext_vector_type(4)));

static constexpr int CB = 8;      // batch
static constexpr int CC = 256;    // channels = Co
static constexpr int CN = 4096;   // tokens = H*W
static constexpr size_t SZ = (size_t)CB * CN * CC;   // one [B,N,256] slab

#define MFMA(a, b, c)   __builtin_amdgcn_mfma_f32_16x16x32_f16((a), (b), (c), 0, 0, 0)
#define MFMA32(a, b, c) __builtin_amdgcn_mfma_f32_32x32x16_f16((a), (b), (c), 0, 0, 0)

__device__ __forceinline__ void gll16(const void* g, void* l) {
  __builtin_amdgcn_global_load_lds(
      (const __attribute__((address_space(1))) unsigned int*)g,
      (__attribute__((address_space(3))) unsigned int*)l, 16, 0, 0);
}

// swap a's lanes 32-63 with b's lanes 0-31 (CDNA4 cross-half exchange)
__device__ __forceinline__ void plswap(u32& a, u32& b) {
  asm volatile("v_permlane32_swap_b32 %0, %1" : "+v"(a), "+v"(b));
}

__device__ __forceinline__ u32 pk(float lo, float hi) {
  auto h = __builtin_amdgcn_cvt_pkrtz(lo, hi);   // __fp16 ext_vector_type(2)
  return __builtin_bit_cast(u32, h);
}

__global__ __launch_bounds__(256) void prep_weights(const float* __restrict__ wq,
    const float* __restrict__ wk, const float* __restrict__ wv,
    const float* __restrict__ wo, f16* __restrict__ W) {
  int i = blockIdx.x * 256 + threadIdx.x;
  W[i]          = (f16)wq[i];
  W[65536 + i]  = (f16)wk[i];
  W[131072 + i] = (f16)wv[i];
  W[196608 + i] = (f16)wo[i];
}

// x [B,C,N] fp32 -> Q [B,N,256] row-major f16; Kf, Vf frag-major f16.
// Frag-major layout (f16 units): frame = 1024B = 512 f16; per batch 128 kv-blocks
// of 16 frames. K element (kv,c): frame ks=c>>4 of blk kv>>5, pos =
// ((kv&31)+32*((c>>3)&1))*8 + (c&7). V element (o,kv): frame (o>>5)*2+((kv&31)>>4),
// pos = ((o&31)+32*((kv>>3)&1))*8 + (kv&7).
__global__ __launch_bounds__(256) void qkv_kernel(const float* __restrict__ x,
    const f16* __restrict__ Wq, const f16* __restrict__ Wk, const f16* __restrict__ Wv,
    const float* __restrict__ bq, const float* __restrict__ bk, const float* __restrict__ bv,
    f16* __restrict__ Q, f16* __restrict__ Kf, f16* __restrict__ Vf) {
  __shared__ f16 xf[64][264];
  const int b  = blockIdx.x >> 6;
  const int n0 = (blockIdx.x & 63) << 6;
  const int t  = threadIdx.x;
  const float* xb = x + (size_t)b * CC * CN;
  {
    int c = t >> 4;
    const int nn = (t & 15) << 2;
    #pragma unroll
    for (int pass = 0; pass < 16; ++pass, c += 16) {
      const float4 v = *(const float4*)(xb + (size_t)c * CN + n0 + nn);
      xf[nn + 0][c] = (f16)v.x;
      xf[nn + 1][c] = (f16)v.y;
      xf[nn + 2][c] = (f16)v.z;
      xf[nn + 3][c] = (f16)v.w;
    }
  }
  __syncthreads();
  const int w = t >> 6, l = t & 63, lr = l & 15, lh = l >> 4;   // lh in 0..3

  f16x8 xff[8];
  #pragma unroll
  for (int kk = 0; kk < 8; ++kk)
    xff[kk] = *(const f16x8*)&xf[w * 16 + lr][kk * 32 + lh * 8];

  const size_t qkrow = ((size_t)b * CN + n0 + w * 16 + lr) * CC;
  // shared frag-store geometry (kv = n0+w*16+lr for K; n = n0+w*16+lh*4 for V)
  const int blkk  = (n0 >> 5) + (w >> 1);
  const int lanek = (w & 1) * 16 + lr + 32 * (lh >> 1);
  const int offk  = (lh & 1) * 4;

  #pragma unroll 1
  for (int mat = 0; mat < 2; ++mat) {
    const f16* W = mat ? Wk : Wq;
    const float* bias = mat ? bk : bq;
    f32x4 acc[16];
    #pragma unroll
    for (int m = 0; m < 16; ++m) acc[m] = f32x4{0.f, 0.f, 0.f, 0.f};
    #pragma unroll
    for (int kk = 0; kk < 8; ++kk) {
      #pragma unroll
      for (int m = 0; m < 16; ++m) {
        f16x8 af = *(const f16x8*)&W[(size_t)(m * 16 + lr) * CC + kk * 32 + lh * 8];
        acc[m] = MFMA(af, xff[kk], acc[m]);
      }
    }
    #pragma unroll
    for (int m = 0; m < 16; ++m) {
      const int o = m * 16 + lh * 4;          // c for this lane (4 consecutive)
      const float4 bs = *(const float4*)&bias[o];
      f16x4 hv;
      hv[0] = (f16)(acc[m][0] + bs.x);
      hv[1] = (f16)(acc[m][1] + bs.y);
      hv[2] = (f16)(acc[m][2] + bs.z);
      hv[3] = (f16)(acc[m][3] + bs.w);
      if (mat == 0) {
        *(f16x4*)&Q[qkrow + o] = hv;          // Q row-major
      } else {                                 // K frag-major: frame ks = m
        *(f16x4*)&Kf[(((size_t)b * 128 + blkk) * 16 + m) * 512 + lanek * 8 + offk] = hv;
      }
    }
  }
  {
    f32x4 acc[16];
    #pragma unroll
    for (int m = 0; m < 16; ++m) acc[m] = f32x4{0.f, 0.f, 0.f, 0.f};
    #pragma unroll
    for (int kk = 0; kk < 8; ++kk) {
      #pragma unroll
      for (int m = 0; m < 16; ++m) {
        f16x8 bf = *(const f16x8*)&Wv[(size_t)(m * 16 + lr) * CC + kk * 32 + lh * 8];
        acc[m] = MFMA(xff[kk], bf, acc[m]);
      }
    }
    // V: lane holds 4 consecutive n = n0+w*16+lh*4.. at fixed o = m*16+lr
    const int blkv = (n0 >> 5) + (w >> 1);
    const int offv = (lh & 1) * 4;
    #pragma unroll
    for (int m = 0; m < 16; ++m) {
      const int o = m * 16 + lr;
      const float bvs = bv[o];
      f16x4 hv;
      #pragma unroll
      for (int j = 0; j < 4; ++j) hv[j] = (f16)(acc[m][j] + bvs);
      const int fr = (m >> 1) * 2 + (w & 1);
      const int lanev = (m & 1) * 16 + lr + 32 * (lh >> 1);
      *(f16x4*)&Vf[(((size_t)b * 128 + blkv) * 16 + fr) * 512 + lanev * 8 + offv] = hv;
    }
  }
}

// flash attention v10: v5 schedule, K in 32KB dbuf LDS (linear gll16 from
// frag-major Kf), V read directly from frag-major Vf global (coalesced, L2),
// 3 blocks/CU. Q row-major in regs. Direct O store.
__global__ __launch_bounds__(256, 3) void attn_kernel(const f16* __restrict__ Q,
    const f16* __restrict__ Kf, const f16* __restrict__ Vf, f16* __restrict__ O) {
  // SMEM: [0,32768) K frames buf*16384 + ks*1024 (frag-linear, lane*16);
  //       [32768, 33280) per-wave alpha floats w*128
  __shared__ __align__(16) char SMEM[33280];

  const int bid = blockIdx.x;
  const int lb = ((bid & 7) << 6) | (bid >> 3);   // XCD swizzle: batch -> XCD
  const int b  = lb >> 6;
  const int q0 = (lb & 63) << 6;                  // 64 q-rows per block
  const int t  = threadIdx.x;
  const int w  = t >> 6, l = t & 63, ln = l & 31, lh = l >> 5;
  const int g  = w >> 1, hv = w & 1;              // q-group, o-half

  const f16* Qb = Q + (size_t)b * CN * CC;
  float* const ALf = (float*)(SMEM + 32768 + w * 128);

  // stage one 32-kv K tile: wave w stages frames 4w..4w+3, each a linear 1KB copy
  auto stageK = [&](int buf, int blk) {
    const f16* src = Kf + (((size_t)b * 128 + blk) * 16 + w * 4) * 512 + l * 8;
    #pragma unroll
    for (int j = 0; j < 4; ++j)
      gll16(src + j * 512, SMEM + (buf << 14) + ((w * 4 + j) << 10));
  };

  // Q fragments in registers: B-operand of swapped QK^T (lane: q=ln, c=16ks+8lh+e)
  const int qrow = q0 + 32 * g + ln;
  f16x8 qf[16];
  #pragma unroll
  for (int ks = 0; ks < 16; ++ks)
    qf[ks] = *(const f16x8*)(Qb + (size_t)qrow * CC + ks * 16 + 8 * lh);

  f32x16 oacc[4];
  #pragma unroll
  for (int ot = 0; ot < 4; ++ot)
    #pragma unroll
    for (int i = 0; i < 16; ++i) oacc[ot][i] = 0.0f;
  float mrun = -3e38f, lrun = 0.0f;

  stageK(0, 0);
  __syncthreads();
  int buf = 0;

  #pragma unroll 1
  for (int it = 0; it < 128; ++it) {
    if (it < 127) stageK(buf ^ 1, it + 1);       // async prefetch, drained at barrier

    // swapped QK^T: S^T[kv][q]; A=K frag (lane: kv=ln, c=16ks+8lh+e), B=Q frag
    f32x16 s;
    #pragma unroll
    for (int i = 0; i < 16; ++i) s[i] = 0.0f;
    __builtin_amdgcn_s_setprio(1);
    #pragma unroll
    for (int ks = 0; ks < 16; ++ks) {
      const f16x8 kf = *(const f16x8*)(SMEM + (buf << 14) + (ks << 10) + l * 16);
      s = MFMA32(kf, qf[ks], s);
    }
    __builtin_amdgcn_s_setprio(0);

    // V direct loads (frag-major, 1KB coalesced each, L2-resident; latency
    // hides under the softmax VALU chain below)
    f16x8 vf[8];
    const f16* vb = Vf + (((size_t)b * 128 + it) * 16 + 8 * hv) * 512 + l * 8;
    #pragma unroll
    for (int j = 0; j < 8; ++j) vf[j] = *(const f16x8*)(vb + j * 512);

    // online softmax: lane owns q=ln; 16 kv in-lane, partner (l^32) has other 16
    float mx8[8], mx4[4];
    #pragma unroll
    for (int i = 0; i < 8; ++i) mx8[i] = fmaxf(s[2 * i], s[2 * i + 1]);
    #pragma unroll
    for (int i = 0; i < 4; ++i) mx4[i] = fmaxf(mx8[2 * i], mx8[2 * i + 1]);
    float pmax = fmaxf(fmaxf(mx4[0], mx4[1]), fmaxf(mx4[2], mx4[3]));
    pmax = fmaxf(pmax, __shfl_xor(pmax, 32));
    const bool need = !__all(pmax - mrun <= 8.0f);      // defer-max (T13)
    const float mnew = need ? fmaxf(mrun, pmax) : mrun;
    float p[16];
    #pragma unroll
    for (int r = 0; r < 16; ++r) p[r] = __expf(s[r] - mnew);  // native v_exp_f32
    float sm8[8], sm4[4];
    #pragma unroll
    for (int i = 0; i < 8; ++i) sm8[i] = p[2 * i] + p[2 * i + 1];
    #pragma unroll
    for (int i = 0; i < 4; ++i) sm4[i] = sm8[2 * i] + sm8[2 * i + 1];
    float psum = (sm4[0] + sm4[1]) + (sm4[2] + sm4[3]);
    psum += __shfl_xor(psum, 32);
    if (need) {                                          // rare rescale path
      const float alpha = __expf(mrun - mnew);
      lrun = lrun * alpha + psum;
      mrun = mnew;
      if (l < 32) ALf[ln] = alpha;                       // lanes l, l^32 agree
      #pragma unroll
      for (int r = 0; r < 16; ++r) {
        const float fr = ALf[(r & 3) + 8 * (r >> 2) + 4 * lh];  // alpha of q(r)
        #pragma unroll
        for (int ot = 0; ot < 4; ++ot) oacc[ot][r] *= fr;
      }
    } else {
      lrun += psum;
    }

    // in-register P relayout: pack f32 pairs -> f16x2 words, cross-half swap
    u32 pw[8];
    #pragma unroll
    for (int i = 0; i < 8; ++i) pw[i] = pk(p[2 * i], p[2 * i + 1]);
    plswap(pw[0], pw[2]); plswap(pw[1], pw[3]);          // kv 0..15
    plswap(pw[4], pw[6]); plswap(pw[5], pw[7]);          // kv 16..31
    const f16x8 pa0 = __builtin_bit_cast(f16x8, u32x4{pw[0], pw[1], pw[2], pw[3]});
    const f16x8 pa1 = __builtin_bit_cast(f16x8, u32x4{pw[4], pw[5], pw[6], pw[7]});

    // PV: D[q][o] += P x V; B=V frag (lane: o=ln, kv=8lh+e); own o-half
    __builtin_amdgcn_s_setprio(1);
    #pragma unroll
    for (int ot = 0; ot < 4; ++ot) {
      oacc[ot] = MFMA32(pa0, vf[2 * ot],     oacc[ot]);
      oacc[ot] = MFMA32(pa1, vf[2 * ot + 1], oacc[ot]);
    }
    __builtin_amdgcn_s_setprio(0);
    __syncthreads();                              // K(it+1) visible; buf reusable
    buf ^= 1;
  }

  // epilogue: direct store of own 32q x 128o slice, scaled by 1/l
  if (l < 32) ALf[ln] = 1.0f / lrun;
  f16* Ob = O + ((size_t)b * CN + q0 + 32 * g) * CC + 128 * hv;
  #pragma unroll
  for (int r = 0; r < 16; ++r) {
    const int q = (r & 3) + 8 * (r >> 2) + 4 * lh;
    const float inv = ALf[q];
    #pragma unroll
    for (int ot = 0; ot < 4; ++ot)
      Ob[(size_t)q * CC + ot * 32 + ln] = (f16)(oacc[ot][r] * inv);
  }
}

// out[b,c,n] = sum_o O[b,n,o] * Wo[c,o] + bo[c]   (verified)
__global__ __launch_bounds__(256) void oproj_kernel(const f16* __restrict__ O,
    const f16* __restrict__ Wo, const float* __restrict__ bo, float* __restrict__ out) {
  const int b  = blockIdx.x >> 6;
  const int n0 = (blockIdx.x & 63) << 6;
  const int t  = threadIdx.x;
  const int w = t >> 6, l = t & 63, lr = l & 15, lh = l >> 4;
  const f16* orow = O + ((size_t)b * CN + n0 + w * 16 + lr) * CC;
  f32x4 acc[16];
  #pragma unroll
  for (int m = 0; m < 16; ++m) acc[m] = f32x4{0.f, 0.f, 0.f, 0.f};
  #pragma unroll
  for (int kk = 0; kk < 8; ++kk) {
    const f16x8 bf = *(const f16x8*)&orow[kk * 32 + lh * 8];
    #pragma unroll
    for (int m = 0; m < 16; ++m) {
      f16x8 af = *(const f16x8*)&Wo[(size_t)(m * 16 + lr) * CC + kk * 32 + lh * 8];
      acc[m] = MFMA(af, bf, acc[m]);
    }
  }
  #pragma unroll
  for (int m = 0; m < 16; ++m) {
    const int c = m * 16 + lh * 4;
    const float4 bv4 = *(const float4*)&bo[c];
    const size_t base = ((size_t)b * CC + c) * CN + n0 + w * 16 + lr;
    out[base + 0 * (size_t)CN] = acc[m][0] + bv4.x;
    out[base + 1 * (size_t)CN] = acc[m][1] + bv4.y;
    out[base + 2 * (size_t)CN] = acc[m][2] + bv4.z;
    out[base + 3 * (size_t)CN] = acc[m][3] + bv4.w;
  }
}

extern "C" void kernel_launch(void* const* d_in, const int* in_sizes, int n_in,
                              void* d_out, int out_size, void* d_ws, size_t ws_size,
                              hipStream_t stream) {
  const float* x  = (const float*)d_in[0];
  const float* wq = (const float*)d_in[1];
  const float* bq = (const float*)d_in[2];
  const float* wk = (const float*)d_in[3];
  const float* bk = (const float*)d_in[4];
  const float* wv = (const float*)d_in[5];
  const float* bv = (const float*)d_in[6];
  const float* wo = (const float*)d_in[7];
  const float* bo = (const float*)d_in[8];

  f16* W  = (f16*)d_ws;                     // 4 x 65536 f16 weights
  f16* Qd = W + 262144;                     // [B,N,256] row-major
  f16* Kf = Qd + SZ;                        // frag-major K
  f16* Vf = Kf + SZ;                        // frag-major V
  f16* Od = Vf + SZ;                        // [B,N,256]

  prep_weights<<<256, 256, 0, stream>>>(wq, wk, wv, wo, W);
  qkv_kernel<<<512, 256, 0, stream>>>(x, W, W + 65536, W + 131072, bq, bk, bv, Qd, Kf, Vf);
  attn_kernel<<<512, 256, 0, stream>>>(Qd, Kf, Vf, Od);
  oproj_kernel<<<512, 256, 0, stream>>>(Od, W + 196608, bo, (float*)d_out);
}

// Round 11
// 390.815 us; speedup vs baseline: 2.2637x; 1.9384x over previous
//
#include <hip/hip_runtime.h>
#include <hip/hip_fp16.h>

typedef _Float16 f16;
typedef _Float16 f16x4 __attribute__((ext_vector_type(4)));
typedef _Float16 f16x8 __attribute__((ext_vector_type(8)));
typedef float f32x4 __attribute__((ext_vector_type(4)));
typedef float f32x16 __attribute__((ext_vector_type(16)));
typedef unsigned int u32;
typedef u32 u32x4 __attribute__((ext_vector_type(4)));

static constexpr int CB = 8;      // batch
static constexpr int CC = 256;    // channels = Co
static constexpr int CN = 4096;   // tokens = H*W

#define MFMA(a, b, c)   __builtin_amdgcn_mfma_f32_16x16x32_f16((a), (b), (c), 0, 0, 0)
#define MFMA32(a, b, c) __builtin_amdgcn_mfma_f32_32x32x16_f16((a), (b), (c), 0, 0, 0)

__device__ __forceinline__ void gll16(const void* g, void* l) {
  __builtin_amdgcn_global_load_lds(
      (const __attribute__((address_space(1))) unsigned int*)g,
      (__attribute__((address_space(3))) unsigned int*)l, 16, 0, 0);
}

// swap a's lanes 32-63 with b's lanes 0-31 (CDNA4 cross-half exchange)
__device__ __forceinline__ void plswap(u32& a, u32& b) {
  asm volatile("v_permlane32_swap_b32 %0, %1" : "+v"(a), "+v"(b));
}

__device__ __forceinline__ u32 pk(float lo, float hi) {
  auto h = __builtin_amdgcn_cvt_pkrtz(lo, hi);   // __fp16 ext_vector_type(2)
  return __builtin_bit_cast(u32, h);
}

__global__ __launch_bounds__(256) void prep_weights(const float* __restrict__ wq,
    const float* __restrict__ wk, const float* __restrict__ wv,
    const float* __restrict__ wo, f16* __restrict__ W) {
  int i = blockIdx.x * 256 + threadIdx.x;
  W[i]          = (f16)wq[i];
  W[65536 + i]  = (f16)wk[i];
  W[131072 + i] = (f16)wv[i];
  W[196608 + i] = (f16)wo[i];
}

// x [B,C,N] fp32  ->  Q,K [B,N,256] f16 ; V^T [B,256,N] f16   (unchanged, verified)
__global__ __launch_bounds__(256) void qkv_kernel(const float* __restrict__ x,
    const f16* __restrict__ Wq, const f16* __restrict__ Wk, const f16* __restrict__ Wv,
    const float* __restrict__ bq, const float* __restrict__ bk, const float* __restrict__ bv,
    f16* __restrict__ Q, f16* __restrict__ K, f16* __restrict__ Vt) {
  __shared__ f16 xf[64][264];
  const int b  = blockIdx.x >> 6;
  const int n0 = (blockIdx.x & 63) << 6;
  const int t  = threadIdx.x;
  const float* xb = x + (size_t)b * CC * CN;
  {
    int c = t >> 4;
    const int nn = (t & 15) << 2;
    #pragma unroll
    for (int pass = 0; pass < 16; ++pass, c += 16) {
      const float4 v = *(const float4*)(xb + (size_t)c * CN + n0 + nn);
      xf[nn + 0][c] = (f16)v.x;
      xf[nn + 1][c] = (f16)v.y;
      xf[nn + 2][c] = (f16)v.z;
      xf[nn + 3][c] = (f16)v.w;
    }
  }
  __syncthreads();
  const int w = t >> 6, l = t & 63, lr = l & 15, lh = l >> 4;

  f16x8 xff[8];
  #pragma unroll
  for (int kk = 0; kk < 8; ++kk)
    xff[kk] = *(const f16x8*)&xf[w * 16 + lr][kk * 32 + lh * 8];

  const size_t qkrow = ((size_t)b * CN + n0 + w * 16 + lr) * CC;

  #pragma unroll 1
  for (int mat = 0; mat < 2; ++mat) {
    const f16* W = mat ? Wk : Wq;
    const float* bias = mat ? bk : bq;
    f16* dst = mat ? K : Q;
    f32x4 acc[16];
    #pragma unroll
    for (int m = 0; m < 16; ++m) acc[m] = f32x4{0.f, 0.f, 0.f, 0.f};
    #pragma unroll
    for (int kk = 0; kk < 8; ++kk) {
      #pragma unroll
      for (int m = 0; m < 16; ++m) {
        f16x8 af = *(const f16x8*)&W[(size_t)(m * 16 + lr) * CC + kk * 32 + lh * 8];
        acc[m] = MFMA(af, xff[kk], acc[m]);
      }
    }
    #pragma unroll
    for (int m = 0; m < 16; ++m) {
      const int o = m * 16 + lh * 4;
      const float4 bs = *(const float4*)&bias[o];
      f16x4 hv;
      hv[0] = (f16)(acc[m][0] + bs.x);
      hv[1] = (f16)(acc[m][1] + bs.y);
      hv[2] = (f16)(acc[m][2] + bs.z);
      hv[3] = (f16)(acc[m][3] + bs.w);
      *(f16x4*)&dst[qkrow + o] = hv;
    }
  }
  {
    f32x4 acc[16];
    #pragma unroll
    for (int m = 0; m < 16; ++m) acc[m] = f32x4{0.f, 0.f, 0.f, 0.f};
    #pragma unroll
    for (int kk = 0; kk < 8; ++kk) {
      #pragma unroll
      for (int m = 0; m < 16; ++m) {
        f16x8 bf = *(const f16x8*)&Wv[(size_t)(m * 16 + lr) * CC + kk * 32 + lh * 8];
        acc[m] = MFMA(xff[kk], bf, acc[m]);
      }
    }
    #pragma unroll
    for (int m = 0; m < 16; ++m) {
      const int o = m * 16 + lr;
      const float bvs = bv[o];
      f16x4 hv;
      #pragma unroll
      for (int j = 0; j < 4; ++j) hv[j] = (f16)(acc[m][j] + bvs);
      *(f16x4*)&Vt[((size_t)b * CC + o) * CN + n0 + w * 16 + lh * 4] = hv;
    }
  }
}

// flash attention v11: P-exchange dedup. Per kv-tile, ONE wave per q-group
// (owner, alternating by tile parity) computes QK^T + softmax and publishes
// P-fragments + alpha/m/l via dbuf LDS; BOTH o-half waves run PV one tile
// later. MFMA per wave-iter: 24 -> avg 16. Memory structure = v6 (proven).
// Q,K [B,N,256], V^T [B,256,N] -> O [B,N,256]
__global__ __launch_bounds__(256, 2) void attn_kernel(const f16* __restrict__ Q,
    const f16* __restrict__ K, const f16* __restrict__ Vt, f16* __restrict__ O) {
  // SMEM (bytes):
  //   [0, 32768):     K frames: buf*16384 + ks*1024 (frag-linear, +16*l)
  //   [32768, 65536): V frames: 32768 + buf*16384 + f*1024
  //   [65536, 73728): P dbuf:   65536 + pbuf*4096 + g*2048 + fr*1024 (+16*l)
  //   [73728, 74240): ML per g: g*256 + {m[32] @0, l[32] @128}  (single-buffered)
  //   [74240, 75264): AF dbuf:  74240 + pbuf*512 + g*256 + {alpha[32] @0, flag @128}
  __shared__ __align__(16) char SMEM[75264];

  const int bid = blockIdx.x;
  const int lb = ((bid & 7) << 6) | (bid >> 3);   // XCD swizzle: batch -> XCD
  const int b  = lb >> 6;
  const int q0 = (lb & 63) << 6;                  // 64 q-rows per block
  const int tid = threadIdx.x;
  const int w  = tid >> 6, l = tid & 63, ln = l & 31, lh = l >> 5;
  const int g  = w >> 1, hv = w & 1;              // q-group, o-half

  const f16* Qb = Q  + (size_t)b * CN * CC;
  const f16* Kb = K  + (size_t)b * CN * CC;
  const f16* Vb = Vt + (size_t)b * CC * CN;

  auto kfrm = [&](int buf, int ks) -> char* { return SMEM + (buf << 14) + (ks << 10); };
  auto vfrm = [&](int buf, int f)  -> char* { return SMEM + 32768 + (buf << 14) + (f << 10); };
  auto pfrm = [&](int pb, int fr)  -> char* { return SMEM + 65536 + (pb << 12) + (g << 11) + (fr << 10); };
  float* const MLm = (float*)(SMEM + 73728 + g * 256);
  float* const MLl = MLm + 32;
  auto AFa = [&](int pb) -> float* { return (float*)(SMEM + 74240 + (pb << 9) + (g << 8)); };

  // staging (as v6): each wave moves 4 K frames + 4 V frames per tile
  auto stageK = [&](int buf, int kv0) {
    const f16* ksrc = Kb + (size_t)(kv0 + ln) * CC + (w * 4) * 16 + 8 * lh;
    #pragma unroll
    for (int j = 0; j < 4; ++j)
      gll16(ksrc + j * 16, kfrm(buf, w * 4 + j));
  };
  auto stageV = [&](int buf, int kv0) {
    #pragma unroll
    for (int p = 0; p < 2; ++p) {
      const int f = w * 4 + 2 * p;
      const f16* vsrc = Vb + (size_t)((f >> 1) * 32 + ln) * CN + kv0 + 8 * lh;
      gll16(vsrc,      vfrm(buf, f));
      gll16(vsrc + 16, vfrm(buf, f + 1));
    }
  };

  // Q fragments (same q-rows for both hv waves of a group)
  const int qrow = q0 + 32 * g + ln;
  f16x8 qf[16];
  #pragma unroll
  for (int ks = 0; ks < 16; ++ks)
    qf[ks] = *(const f16x8*)(Qb + (size_t)qrow * CC + ks * 16 + 8 * lh);

  f32x16 oacc[4];
  #pragma unroll
  for (int ot = 0; ot < 4; ++ot)
    #pragma unroll
    for (int i = 0; i < 16; ++i) oacc[ot][i] = 0.0f;

  // PV of tile with data in buffer pb (rescale by alpha(pb) first)
  auto pvstep = [&](int pb) {
    const float* af = AFa(pb);
    const float flag = af[32];
    if (flag != 0.0f) {
      #pragma unroll
      for (int r = 0; r < 16; ++r) {
        const float fr = af[(r & 3) + 8 * (r >> 2) + 4 * lh];
        #pragma unroll
        for (int ot = 0; ot < 4; ++ot) oacc[ot][r] *= fr;
      }
    }
    const f16x8 pa0 = *(const f16x8*)(pfrm(pb, 0) + l * 16);
    const f16x8 pa1 = *(const f16x8*)(pfrm(pb, 1) + l * 16);
    __builtin_amdgcn_s_setprio(1);
    #pragma unroll
    for (int ot = 0; ot < 4; ++ot) {
      const int f0 = 8 * hv + 2 * ot;
      const f16x8 v0 = *(const f16x8*)(vfrm(pb, f0) + l * 16);
      oacc[ot] = MFMA32(pa0, v0, oacc[ot]);
      const f16x8 v1 = *(const f16x8*)(vfrm(pb, f0 + 1) + l * 16);
      oacc[ot] = MFMA32(pa1, v1, oacc[ot]);
    }
    __builtin_amdgcn_s_setprio(0);
  };

  stageK(0, 0);
  __syncthreads();                                // K(0) ready

  #pragma unroll 1
  for (int it = 0; it < 128; ++it) {
    const int cur = it & 1, prv = cur ^ 1;
    if (it < 127) stageK(prv, (it + 1) * 32);     // K(it+1), drained at barrier
    stageV(cur, it * 32);                         // V(it), read next iter

    const bool own = (hv == cur);                 // wave-uniform

    // owner: QK(it) — long MFMA chain issued first
    f32x16 s;
    if (own) {
      #pragma unroll
      for (int i = 0; i < 16; ++i) s[i] = 0.0f;
      __builtin_amdgcn_s_setprio(1);
      #pragma unroll
      for (int ks = 0; ks < 16; ++ks) {
        const f16x8 kf = *(const f16x8*)(kfrm(cur, ks) + l * 16);
        s = MFMA32(kf, qf[ks], s);
      }
      __builtin_amdgcn_s_setprio(0);
    }

    // all waves: PV(it-1)
    if (it > 0) pvstep(prv);

    // owner: softmax(it) + publish P/alpha/m/l
    if (own) {
      const float mprev = it ? MLm[ln] : -3e38f;
      const float lprev = it ? MLl[ln] : 0.0f;
      float mx8[8], mx4[4];
      #pragma unroll
      for (int i = 0; i < 8; ++i) mx8[i] = fmaxf(s[2 * i], s[2 * i + 1]);
      #pragma unroll
      for (int i = 0; i < 4; ++i) mx4[i] = fmaxf(mx8[2 * i], mx8[2 * i + 1]);
      float pmax = fmaxf(fmaxf(mx4[0], mx4[1]), fmaxf(mx4[2], mx4[3]));
      pmax = fmaxf(pmax, __shfl_xor(pmax, 32));
      const bool need = !__all(pmax - mprev <= 8.0f);   // defer-max (T13)
      const float mnew = need ? fmaxf(mprev, pmax) : mprev;
      float p[16];
      #pragma unroll
      for (int r = 0; r < 16; ++r) p[r] = __expf(s[r] - mnew);
      float sm8[8], sm4[4];
      #pragma unroll
      for (int i = 0; i < 8; ++i) sm8[i] = p[2 * i] + p[2 * i + 1];
      #pragma unroll
      for (int i = 0; i < 4; ++i) sm4[i] = sm8[2 * i] + sm8[2 * i + 1];
      float psum = (sm4[0] + sm4[1]) + (sm4[2] + sm4[3]);
      psum += __shfl_xor(psum, 32);
      float alpha = 1.0f, lnew;
      if (need) { alpha = __expf(mprev - mnew); lnew = lprev * alpha + psum; }
      else      { lnew = lprev + psum; }
      if (l < 32) {
        MLm[ln] = mnew;
        MLl[ln] = lnew;
        float* af = AFa(cur);
        af[ln] = alpha;
        if (ln == 0) af[32] = need ? 1.0f : 0.0f;
      }
      // pack P -> A-frag words, publish to pbuf[cur]
      u32 pw[8];
      #pragma unroll
      for (int i = 0; i < 8; ++i) pw[i] = pk(p[2 * i], p[2 * i + 1]);
      plswap(pw[0], pw[2]); plswap(pw[1], pw[3]);
      plswap(pw[4], pw[6]); plswap(pw[5], pw[7]);
      *(u32x4*)(pfrm(cur, 0) + l * 16) = u32x4{pw[0], pw[1], pw[2], pw[3]};
      *(u32x4*)(pfrm(cur, 1) + l * 16) = u32x4{pw[4], pw[5], pw[6], pw[7]};
    }
    __syncthreads();   // drains K(it+1)/V(it); publishes P/ML/AF(it)
  }

  // epilogue: PV(127) (data in buffers pb=1), then normalized store
  pvstep(1);

  f16* Ob = O + ((size_t)b * CN + q0 + 32 * g) * CC + 128 * hv;
  #pragma unroll
  for (int r = 0; r < 16; ++r) {
    const int q = (r & 3) + 8 * (r >> 2) + 4 * lh;
    const float inv = 1.0f / MLl[q];
    #pragma unroll
    for (int ot = 0; ot < 4; ++ot)
      Ob[(size_t)q * CC + ot * 32 + ln] = (f16)(oacc[ot][r] * inv);
  }
}

// out[b,c,n] = sum_o O[b,n,o] * Wo[c,o] + bo[c]   (verified)
__global__ __launch_bounds__(256) void oproj_kernel(const f16* __restrict__ O,
    const f16* __restrict__ Wo, const float* __restrict__ bo, float* __restrict__ out) {
  const int b  = blockIdx.x >> 6;
  const int n0 = (blockIdx.x & 63) << 6;
  const int t  = threadIdx.x;
  const int w = t >> 6, l = t & 63, lr = l & 15, lh = l >> 4;
  const f16* orow = O + ((size_t)b * CN + n0 + w * 16 + lr) * CC;
  f32x4 acc[16];
  #pragma unroll
  for (int m = 0; m < 16; ++m) acc[m] = f32x4{0.f, 0.f, 0.f, 0.f};
  #pragma unroll
  for (int kk = 0; kk < 8; ++kk) {
    const f16x8 bf = *(const f16x8*)&orow[kk * 32 + lh * 8];
    #pragma unroll
    for (int m = 0; m < 16; ++m) {
      f16x8 af = *(const f16x8*)&Wo[(size_t)(m * 16 + lr) * CC + kk * 32 + lh * 8];
      acc[m] = MFMA(af, bf, acc[m]);
    }
  }
  #pragma unroll
  for (int m = 0; m < 16; ++m) {
    const int c = m * 16 + lh * 4;
    const float4 bv4 = *(const float4*)&bo[c];
    const size_t base = ((size_t)b * CC + c) * CN + n0 + w * 16 + lr;
    out[base + 0 * (size_t)CN] = acc[m][0] + bv4.x;
    out[base + 1 * (size_t)CN] = acc[m][1] + bv4.y;
    out[base + 2 * (size_t)CN] = acc[m][2] + bv4.z;
    out[base + 3 * (size_t)CN] = acc[m][3] + bv4.w;
  }
}

extern "C" void kernel_launch(void* const* d_in, const int* in_sizes, int n_in,
                              void* d_out, int out_size, void* d_ws, size_t ws_size,
                              hipStream_t stream) {
  const float* x  = (const float*)d_in[0];
  const float* wq = (const float*)d_in[1];
  const float* bq = (const float*)d_in[2];
  const float* wk = (const float*)d_in[3];
  const float* bk = (const float*)d_in[4];
  const float* wv = (const float*)d_in[5];
  const float* bv = (const float*)d_in[6];
  const float* wo = (const float*)d_in[7];
  const float* bo = (const float*)d_in[8];

  f16* W  = (f16*)d_ws;                     // 4 x 65536 f16 weights
  f16* Qd = W + 262144;                     // [B,N,256]
  f16* Kd = Qd + (size_t)CB * CN * CC;      // [B,N,256]
  f16* Vt = Kd + (size_t)CB * CN * CC;      // [B,256,N]
  f16* Od = Vt + (size_t)CB * CN * CC;      // [B,N,256]

  prep_weights<<<256, 256, 0, stream>>>(wq, wk, wv, wo, W);
  qkv_kernel<<<512, 256, 0, stream>>>(x, W, W + 65536, W + 131072, bq, bk, bv, Qd, Kd, Vt);
  attn_kernel<<<512, 256, 0, stream>>>(Qd, Kd, Vt, Od);
  oproj_kernel<<<512, 256, 0, stream>>>(Od, W + 196608, bo, (float*)d_out);
}

// Round 12
// 378.213 us; speedup vs baseline: 2.3391x; 1.0333x over previous
//
#include <hip/hip_runtime.h>
#include <hip/hip_fp16.h>

typedef _Float16 f16;
typedef _Float16 f16x4 __attribute__((ext_vector_type(4)));
typedef _Float16 f16x8 __attribute__((ext_vector_type(8)));
typedef float f32x4 __attribute__((ext_vector_type(4)));
typedef float f32x16 __attribute__((ext_vector_type(16)));
typedef unsigned int u32;
typedef u32 u32x4 __attribute__((ext_vector_type(4)));

static constexpr int CB = 8;      // batch
static constexpr int CC = 256;    // channels = Co
static constexpr int CN = 4096;   // tokens = H*W

#define MFMA(a, b, c)   __builtin_amdgcn_mfma_f32_16x16x32_f16((a), (b), (c), 0, 0, 0)
#define MFMA32(a, b, c) __builtin_amdgcn_mfma_f32_32x32x16_f16((a), (b), (c), 0, 0, 0)

__device__ __forceinline__ void gll16(const void* g, void* l) {
  __builtin_amdgcn_global_load_lds(
      (const __attribute__((address_space(1))) unsigned int*)g,
      (__attribute__((address_space(3))) unsigned int*)l, 16, 0, 0);
}

// swap a's lanes 32-63 with b's lanes 0-31 (CDNA4 cross-half exchange)
__device__ __forceinline__ void plswap(u32& a, u32& b) {
  asm volatile("v_permlane32_swap_b32 %0, %1" : "+v"(a), "+v"(b));
}

__device__ __forceinline__ u32 pk(float lo, float hi) {
  auto h = __builtin_amdgcn_cvt_pkrtz(lo, hi);   // __fp16 ext_vector_type(2)
  return __builtin_bit_cast(u32, h);
}

__global__ __launch_bounds__(256) void prep_weights(const float* __restrict__ wq,
    const float* __restrict__ wk, const float* __restrict__ wv,
    const float* __restrict__ wo, f16* __restrict__ W) {
  int i = blockIdx.x * 256 + threadIdx.x;
  W[i]          = (f16)wq[i];
  W[65536 + i]  = (f16)wk[i];
  W[131072 + i] = (f16)wv[i];
  W[196608 + i] = (f16)wo[i];
}

// x [B,C,N] fp32  ->  Q,K [B,N,256] f16 ; V^T [B,256,N] f16   (unchanged, verified)
__global__ __launch_bounds__(256) void qkv_kernel(const float* __restrict__ x,
    const f16* __restrict__ Wq, const f16* __restrict__ Wk, const f16* __restrict__ Wv,
    const float* __restrict__ bq, const float* __restrict__ bk, const float* __restrict__ bv,
    f16* __restrict__ Q, f16* __restrict__ K, f16* __restrict__ Vt) {
  __shared__ f16 xf[64][264];
  const int b  = blockIdx.x >> 6;
  const int n0 = (blockIdx.x & 63) << 6;
  const int t  = threadIdx.x;
  const float* xb = x + (size_t)b * CC * CN;
  {
    int c = t >> 4;
    const int nn = (t & 15) << 2;
    #pragma unroll
    for (int pass = 0; pass < 16; ++pass, c += 16) {
      const float4 v = *(const float4*)(xb + (size_t)c * CN + n0 + nn);
      xf[nn + 0][c] = (f16)v.x;
      xf[nn + 1][c] = (f16)v.y;
      xf[nn + 2][c] = (f16)v.z;
      xf[nn + 3][c] = (f16)v.w;
    }
  }
  __syncthreads();
  const int w = t >> 6, l = t & 63, lr = l & 15, lh = l >> 4;

  f16x8 xff[8];
  #pragma unroll
  for (int kk = 0; kk < 8; ++kk)
    xff[kk] = *(const f16x8*)&xf[w * 16 + lr][kk * 32 + lh * 8];

  const size_t qkrow = ((size_t)b * CN + n0 + w * 16 + lr) * CC;

  #pragma unroll 1
  for (int mat = 0; mat < 2; ++mat) {
    const f16* W = mat ? Wk : Wq;
    const float* bias = mat ? bk : bq;
    f16* dst = mat ? K : Q;
    f32x4 acc[16];
    #pragma unroll
    for (int m = 0; m < 16; ++m) acc[m] = f32x4{0.f, 0.f, 0.f, 0.f};
    #pragma unroll
    for (int kk = 0; kk < 8; ++kk) {
      #pragma unroll
      for (int m = 0; m < 16; ++m) {
        f16x8 af = *(const f16x8*)&W[(size_t)(m * 16 + lr) * CC + kk * 32 + lh * 8];
        acc[m] = MFMA(af, xff[kk], acc[m]);
      }
    }
    #pragma unroll
    for (int m = 0; m < 16; ++m) {
      const int o = m * 16 + lh * 4;
      const float4 bs = *(const float4*)&bias[o];
      f16x4 hv;
      hv[0] = (f16)(acc[m][0] + bs.x);
      hv[1] = (f16)(acc[m][1] + bs.y);
      hv[2] = (f16)(acc[m][2] + bs.z);
      hv[3] = (f16)(acc[m][3] + bs.w);
      *(f16x4*)&dst[qkrow + o] = hv;
    }
  }
  {
    f32x4 acc[16];
    #pragma unroll
    for (int m = 0; m < 16; ++m) acc[m] = f32x4{0.f, 0.f, 0.f, 0.f};
    #pragma unroll
    for (int kk = 0; kk < 8; ++kk) {
      #pragma unroll
      for (int m = 0; m < 16; ++m) {
        f16x8 bf = *(const f16x8*)&Wv[(size_t)(m * 16 + lr) * CC + kk * 32 + lh * 8];
        acc[m] = MFMA(xff[kk], bf, acc[m]);
      }
    }
    #pragma unroll
    for (int m = 0; m < 16; ++m) {
      const int o = m * 16 + lr;
      const float bvs = bv[o];
      f16x4 hv;
      #pragma unroll
      for (int j = 0; j < 4; ++j) hv[j] = (f16)(acc[m][j] + bvs);
      *(f16x4*)&Vt[((size_t)b * CC + o) * CN + n0 + w * 16 + lh * 4] = hv;
    }
  }
}

// flash attention v12: v11 P-exchange dedup + block-parity desync + dual QK
// chains + FUSED out-projection (O-tile via LDS, out = O @ Wo^T + bo direct
// to d_out fp32). Q,K [B,N,256], V^T [B,256,N], Wo [256,256] -> out [B,C,N]
__global__ __launch_bounds__(256, 2) void attn_kernel(const f16* __restrict__ Q,
    const f16* __restrict__ K, const f16* __restrict__ Vt,
    const f16* __restrict__ Wo, const float* __restrict__ bo,
    float* __restrict__ out) {
  // SMEM (bytes):
  //   [0, 32768):     K frames: buf*16384 + ks*1024 (frag-linear, +16*l)
  //   [32768, 65536): V frames: 32768 + buf*16384 + f*1024
  //   [65536, 73728): P dbuf:   65536 + pbuf*4096 + g*2048 + fr*1024 (+16*l)
  //   [73728, 74240): ML per g: g*256 + {m[32] @0, l[32] @128}  (single-buffered)
  //   [74240, 75264): AF dbuf:  74240 + pbuf*512 + g*256 + {alpha[32] @0, flag @128}
  //   epilogue reuse: [0, 33792) = O-tile [64][264] f16 (2-way banks)
  __shared__ __align__(16) char SMEM[75264];

  const int bid = blockIdx.x;
  const int lb = ((bid & 7) << 6) | (bid >> 3);   // XCD swizzle: batch -> XCD
  const int b  = lb >> 6;
  const int q0 = (lb & 63) << 6;                  // 64 q-rows per block
  const int par = (bid >> 3) & 1;                 // desync co-resident blocks
  const int tid = threadIdx.x;
  const int w  = tid >> 6, l = tid & 63, ln = l & 31, lh = l >> 5;
  const int g  = w >> 1, hv = w & 1;              // q-group, o-half

  const f16* Qb = Q  + (size_t)b * CN * CC;
  const f16* Kb = K  + (size_t)b * CN * CC;
  const f16* Vb = Vt + (size_t)b * CC * CN;

  auto kfrm = [&](int buf, int ks) -> char* { return SMEM + (buf << 14) + (ks << 10); };
  auto vfrm = [&](int buf, int f)  -> char* { return SMEM + 32768 + (buf << 14) + (f << 10); };
  auto pfrm = [&](int pb, int fr)  -> char* { return SMEM + 65536 + (pb << 12) + (g << 11) + (fr << 10); };
  float* const MLm = (float*)(SMEM + 73728 + g * 256);
  float* const MLl = MLm + 32;
  auto AFa = [&](int pb) -> float* { return (float*)(SMEM + 74240 + (pb << 9) + (g << 8)); };

  // staging (as v6): each wave moves 4 K frames + 4 V frames per tile
  auto stageK = [&](int buf, int kv0) {
    const f16* ksrc = Kb + (size_t)(kv0 + ln) * CC + (w * 4) * 16 + 8 * lh;
    #pragma unroll
    for (int j = 0; j < 4; ++j)
      gll16(ksrc + j * 16, kfrm(buf, w * 4 + j));
  };
  auto stageV = [&](int buf, int kv0) {
    #pragma unroll
    for (int p = 0; p < 2; ++p) {
      const int f = w * 4 + 2 * p;
      const f16* vsrc = Vb + (size_t)((f >> 1) * 32 + ln) * CN + kv0 + 8 * lh;
      gll16(vsrc,      vfrm(buf, f));
      gll16(vsrc + 16, vfrm(buf, f + 1));
    }
  };

  // Q fragments (same q-rows for both hv waves of a group)
  const int qrow = q0 + 32 * g + ln;
  f16x8 qf[16];
  #pragma unroll
  for (int ks = 0; ks < 16; ++ks)
    qf[ks] = *(const f16x8*)(Qb + (size_t)qrow * CC + ks * 16 + 8 * lh);

  f32x16 oacc[4];
  #pragma unroll
  for (int ot = 0; ot < 4; ++ot)
    #pragma unroll
    for (int i = 0; i < 16; ++i) oacc[ot][i] = 0.0f;

  // PV of tile with data in buffer pb (rescale by alpha(pb) first)
  auto pvstep = [&](int pb) {
    const float* af = AFa(pb);
    const float flag = af[32];
    if (flag != 0.0f) {
      #pragma unroll
      for (int r = 0; r < 16; ++r) {
        const float fr = af[(r & 3) + 8 * (r >> 2) + 4 * lh];
        #pragma unroll
        for (int ot = 0; ot < 4; ++ot) oacc[ot][r] *= fr;
      }
    }
    const f16x8 pa0 = *(const f16x8*)(pfrm(pb, 0) + l * 16);
    const f16x8 pa1 = *(const f16x8*)(pfrm(pb, 1) + l * 16);
    __builtin_amdgcn_s_setprio(1);
    #pragma unroll
    for (int ot = 0; ot < 4; ++ot) {
      const int f0 = 8 * hv + 2 * ot;
      const f16x8 v0 = *(const f16x8*)(vfrm(pb, f0) + l * 16);
      oacc[ot] = MFMA32(pa0, v0, oacc[ot]);
      const f16x8 v1 = *(const f16x8*)(vfrm(pb, f0 + 1) + l * 16);
      oacc[ot] = MFMA32(pa1, v1, oacc[ot]);
    }
    __builtin_amdgcn_s_setprio(0);
  };

  stageK(0, 0);
  __syncthreads();                                // K(0) ready

  #pragma unroll 1
  for (int it = 0; it < 128; ++it) {
    const int cur = it & 1, prv = cur ^ 1;
    if (it < 127) stageK(prv, (it + 1) * 32);     // K(it+1), drained at barrier
    stageV(cur, it * 32);                         // V(it), read next iter

    const bool own = (hv == ((it + par) & 1));    // wave-uniform, desynced

    // owner: QK(it) — dual 8-deep MFMA chains
    f32x16 s;
    if (own) {
      f32x16 sa, sb;
      #pragma unroll
      for (int i = 0; i < 16; ++i) { sa[i] = 0.0f; sb[i] = 0.0f; }
      __builtin_amdgcn_s_setprio(1);
      #pragma unroll
      for (int ks = 0; ks < 8; ++ks) {
        const f16x8 kf0 = *(const f16x8*)(kfrm(cur, ks) + l * 16);
        sa = MFMA32(kf0, qf[ks], sa);
        const f16x8 kf1 = *(const f16x8*)(kfrm(cur, ks + 8) + l * 16);
        sb = MFMA32(kf1, qf[ks + 8], sb);
      }
      __builtin_amdgcn_s_setprio(0);
      #pragma unroll
      for (int i = 0; i < 16; ++i) s[i] = sa[i] + sb[i];
    }

    // all waves: PV(it-1)
    if (it > 0) pvstep(prv);

    // owner: softmax(it) + publish P/alpha/m/l
    if (own) {
      const float mprev = it ? MLm[ln] : -3e38f;
      const float lprev = it ? MLl[ln] : 0.0f;
      float mx8[8], mx4[4];
      #pragma unroll
      for (int i = 0; i < 8; ++i) mx8[i] = fmaxf(s[2 * i], s[2 * i + 1]);
      #pragma unroll
      for (int i = 0; i < 4; ++i) mx4[i] = fmaxf(mx8[2 * i], mx8[2 * i + 1]);
      float pmax = fmaxf(fmaxf(mx4[0], mx4[1]), fmaxf(mx4[2], mx4[3]));
      pmax = fmaxf(pmax, __shfl_xor(pmax, 32));
      const bool need = !__all(pmax - mprev <= 8.0f);   // defer-max (T13)
      const float mnew = need ? fmaxf(mprev, pmax) : mprev;
      float p[16];
      #pragma unroll
      for (int r = 0; r < 16; ++r) p[r] = __expf(s[r] - mnew);
      float sm8[8], sm4[4];
      #pragma unroll
      for (int i = 0; i < 8; ++i) sm8[i] = p[2 * i] + p[2 * i + 1];
      #pragma unroll
      for (int i = 0; i < 4; ++i) sm4[i] = sm8[2 * i] + sm8[2 * i + 1];
      float psum = (sm4[0] + sm4[1]) + (sm4[2] + sm4[3]);
      psum += __shfl_xor(psum, 32);
      float alpha = 1.0f, lnew;
      if (need) { alpha = __expf(mprev - mnew); lnew = lprev * alpha + psum; }
      else      { lnew = lprev + psum; }
      if (l < 32) {
        MLm[ln] = mnew;
        MLl[ln] = lnew;
        float* af = AFa(cur);
        af[ln] = alpha;
        if (ln == 0) af[32] = need ? 1.0f : 0.0f;
      }
      // pack P -> A-frag words, publish to pbuf[cur]
      u32 pw[8];
      #pragma unroll
      for (int i = 0; i < 8; ++i) pw[i] = pk(p[2 * i], p[2 * i + 1]);
      plswap(pw[0], pw[2]); plswap(pw[1], pw[3]);
      plswap(pw[4], pw[6]); plswap(pw[5], pw[7]);
      *(u32x4*)(pfrm(cur, 0) + l * 16) = u32x4{pw[0], pw[1], pw[2], pw[3]};
      *(u32x4*)(pfrm(cur, 1) + l * 16) = u32x4{pw[4], pw[5], pw[6], pw[7]};
    }
    __syncthreads();   // drains K(it+1)/V(it); publishes P/ML/AF(it)
  }

  // epilogue part 1: PV(127) (buffers pb=1), grab 1/l values
  pvstep(1);
  float invv[16];
  #pragma unroll
  for (int r = 0; r < 16; ++r)
    invv[r] = 1.0f / MLl[(r & 3) + 8 * (r >> 2) + 4 * lh];
  __syncthreads();                                // everyone done with K/ML regions

  // epilogue part 2: normalized O-tile -> LDS [64][264] f16
  f16* const OT = (f16*)SMEM;
  #pragma unroll
  for (int r = 0; r < 16; ++r) {
    const int q = (r & 3) + 8 * (r >> 2) + 4 * lh;
    const int qq = 32 * g + q;
    #pragma unroll
    for (int ot = 0; ot < 4; ++ot)
      OT[qq * 264 + 128 * hv + ot * 32 + ln] = (f16)(oacc[ot][r] * invv[r]);
  }
  __syncthreads();

  // epilogue part 3: fused out-projection (verified oproj body, bf from LDS)
  {
    const int lr = l & 15, lq = l >> 4;           // 16x4 lane split
    const f16* orow = OT + (w * 16 + lr) * 264;
    f32x4 acc[16];
    #pragma unroll
    for (int m = 0; m < 16; ++m) acc[m] = f32x4{0.f, 0.f, 0.f, 0.f};
    #pragma unroll
    for (int kk = 0; kk < 8; ++kk) {
      const f16x8 bf = *(const f16x8*)&orow[kk * 32 + lq * 8];
      #pragma unroll
      for (int m = 0; m < 16; ++m) {
        f16x8 af = *(const f16x8*)&Wo[(size_t)(m * 16 + lr) * CC + kk * 32 + lq * 8];
        acc[m] = MFMA(af, bf, acc[m]);
      }
    }
    #pragma unroll
    for (int m = 0; m < 16; ++m) {
      const int c = m * 16 + lq * 4;
      const float4 bv4 = *(const float4*)&bo[c];
      const size_t base = ((size_t)b * CC + c) * CN + q0 + w * 16 + lr;
      out[base + 0 * (size_t)CN] = acc[m][0] + bv4.x;
      out[base + 1 * (size_t)CN] = acc[m][1] + bv4.y;
      out[base + 2 * (size_t)CN] = acc[m][2] + bv4.z;
      out[base + 3 * (size_t)CN] = acc[m][3] + bv4.w;
    }
  }
}

extern "C" void kernel_launch(void* const* d_in, const int* in_sizes, int n_in,
                              void* d_out, int out_size, void* d_ws, size_t ws_size,
                              hipStream_t stream) {
  const float* x  = (const float*)d_in[0];
  const float* wq = (const float*)d_in[1];
  const float* bq = (const float*)d_in[2];
  const float* wk = (const float*)d_in[3];
  const float* bk = (const float*)d_in[4];
  const float* wv = (const float*)d_in[5];
  const float* bv = (const float*)d_in[6];
  const float* wo = (const float*)d_in[7];
  const float* bo = (const float*)d_in[8];

  f16* W  = (f16*)d_ws;                     // 4 x 65536 f16 weights
  f16* Qd = W + 262144;                     // [B,N,256]
  f16* Kd = Qd + (size_t)CB * CN * CC;      // [B,N,256]
  f16* Vt = Kd + (size_t)CB * CN * CC;      // [B,256,N]

  prep_weights<<<256, 256, 0, stream>>>(wq, wk, wv, wo, W);
  qkv_kernel<<<512, 256, 0, stream>>>(x, W, W + 65536, W + 131072, bq, bk, bv, Qd, Kd, Vt);
  attn_kernel<<<512, 256, 0, stream>>>(Qd, Kd, Vt, W + 196608, bo, (float*)d_out);
}

// Round 13
// 377.879 us; speedup vs baseline: 2.3412x; 1.0009x over previous
//
#include <hip/hip_runtime.h>
#include <hip/hip_fp16.h>

typedef _Float16 f16;
typedef _Float16 f16x4 __attribute__((ext_vector_type(4)));
typedef _Float16 f16x8 __attribute__((ext_vector_type(8)));
typedef float f32x4 __attribute__((ext_vector_type(4)));
typedef float f32x16 __attribute__((ext_vector_type(16)));
typedef unsigned int u32;
typedef u32 u32x4 __attribute__((ext_vector_type(4)));

static constexpr int CB = 8;      // batch
static constexpr int CC = 256;    // channels = Co
static constexpr int CN = 4096;   // tokens = H*W

#define MFMA(a, b, c)   __builtin_amdgcn_mfma_f32_16x16x32_f16((a), (b), (c), 0, 0, 0)
#define MFMA32(a, b, c) __builtin_amdgcn_mfma_f32_32x32x16_f16((a), (b), (c), 0, 0, 0)

__device__ __forceinline__ void gll16(const void* g, void* l) {
  __builtin_amdgcn_global_load_lds(
      (const __attribute__((address_space(1))) unsigned int*)g,
      (__attribute__((address_space(3))) unsigned int*)l, 16, 0, 0);
}

// swap a's lanes 32-63 with b's lanes 0-31 (CDNA4 cross-half exchange)
__device__ __forceinline__ void plswap(u32& a, u32& b) {
  asm volatile("v_permlane32_swap_b32 %0, %1" : "+v"(a), "+v"(b));
}

__device__ __forceinline__ u32 pk(float lo, float hi) {
  auto h = __builtin_amdgcn_cvt_pkrtz(lo, hi);   // __fp16 ext_vector_type(2)
  return __builtin_bit_cast(u32, h);
}

__global__ __launch_bounds__(256) void prep_weights(const float* __restrict__ wq,
    const float* __restrict__ wk, const float* __restrict__ wv,
    const float* __restrict__ wo, f16* __restrict__ W) {
  int i = blockIdx.x * 256 + threadIdx.x;
  W[i]          = (f16)wq[i];
  W[65536 + i]  = (f16)wk[i];
  W[131072 + i] = (f16)wv[i];
  W[196608 + i] = (f16)wo[i];
}

// qkv v2: 32-row tiles, m-split across wave pairs -> grid 1024, 4 blocks/CU,
// 4 waves/SIMD. x [B,C,N] fp32 -> Q,K [B,N,256] f16 ; V^T [B,256,N] f16.
// Same math/addressing as the verified 64-row version with w -> rg, m -> mh*8+mm.
__global__ __launch_bounds__(256) void qkv_kernel(const float* __restrict__ x,
    const f16* __restrict__ Wq, const f16* __restrict__ Wk, const f16* __restrict__ Wv,
    const float* __restrict__ bq, const float* __restrict__ bk, const float* __restrict__ bv,
    f16* __restrict__ Q, f16* __restrict__ K, f16* __restrict__ Vt) {
  __shared__ f16 xf[32][264];
  const int b  = blockIdx.x >> 7;
  const int n0 = (blockIdx.x & 127) << 5;
  const int t  = threadIdx.x;
  const float* xb = x + (size_t)b * CC * CN;
  {
    int c = t >> 3;                         // 0..31
    const int nn = (t & 7) << 2;            // 0,4,...,28
    #pragma unroll
    for (int pass = 0; pass < 8; ++pass, c += 32) {
      const float4 v = *(const float4*)(xb + (size_t)c * CN + n0 + nn);
      xf[nn + 0][c] = (f16)v.x;
      xf[nn + 1][c] = (f16)v.y;
      xf[nn + 2][c] = (f16)v.z;
      xf[nn + 3][c] = (f16)v.w;
    }
  }
  __syncthreads();
  const int w = t >> 6, l = t & 63, lr = l & 15, lh = l >> 4;
  const int rg = w >> 1, mh = w & 1;        // row-group, m-half

  f16x8 xff[8];
  #pragma unroll
  for (int kk = 0; kk < 8; ++kk)
    xff[kk] = *(const f16x8*)&xf[rg * 16 + lr][kk * 32 + lh * 8];

  const size_t qkrow = ((size_t)b * CN + n0 + rg * 16 + lr) * CC;

  #pragma unroll 1
  for (int mat = 0; mat < 2; ++mat) {
    const f16* W = mat ? Wk : Wq;
    const float* bias = mat ? bk : bq;
    f16* dst = mat ? K : Q;
    f32x4 acc[8];
    #pragma unroll
    for (int mm = 0; mm < 8; ++mm) acc[mm] = f32x4{0.f, 0.f, 0.f, 0.f};
    #pragma unroll
    for (int kk = 0; kk < 8; ++kk) {
      #pragma unroll
      for (int mm = 0; mm < 8; ++mm) {
        const int m = mh * 8 + mm;
        f16x8 af = *(const f16x8*)&W[(size_t)(m * 16 + lr) * CC + kk * 32 + lh * 8];
        acc[mm] = MFMA(af, xff[kk], acc[mm]);
      }
    }
    #pragma unroll
    for (int mm = 0; mm < 8; ++mm) {
      const int o = (mh * 8 + mm) * 16 + lh * 4;
      const float4 bs = *(const float4*)&bias[o];
      f16x4 hv;
      hv[0] = (f16)(acc[mm][0] + bs.x);
      hv[1] = (f16)(acc[mm][1] + bs.y);
      hv[2] = (f16)(acc[mm][2] + bs.z);
      hv[3] = (f16)(acc[mm][3] + bs.w);
      *(f16x4*)&dst[qkrow + o] = hv;
    }
  }
  {
    f32x4 acc[8];
    #pragma unroll
    for (int mm = 0; mm < 8; ++mm) acc[mm] = f32x4{0.f, 0.f, 0.f, 0.f};
    #pragma unroll
    for (int kk = 0; kk < 8; ++kk) {
      #pragma unroll
      for (int mm = 0; mm < 8; ++mm) {
        const int m = mh * 8 + mm;
        f16x8 bf = *(const f16x8*)&Wv[(size_t)(m * 16 + lr) * CC + kk * 32 + lh * 8];
        acc[mm] = MFMA(xff[kk], bf, acc[mm]);
      }
    }
    #pragma unroll
    for (int mm = 0; mm < 8; ++mm) {
      const int o = (mh * 8 + mm) * 16 + lr;
      const float bvs = bv[o];
      f16x4 hv;
      #pragma unroll
      for (int j = 0; j < 4; ++j) hv[j] = (f16)(acc[mm][j] + bvs);
      *(f16x4*)&Vt[((size_t)b * CC + o) * CN + n0 + rg * 16 + lh * 4] = hv;
    }
  }
}

// flash attention v12 (unchanged, verified): P-exchange dedup + desync + dual QK
// chains + fused out-projection. Q,K [B,N,256], V^T [B,256,N], Wo -> out [B,C,N]
__global__ __launch_bounds__(256, 2) void attn_kernel(const f16* __restrict__ Q,
    const f16* __restrict__ K, const f16* __restrict__ Vt,
    const f16* __restrict__ Wo, const float* __restrict__ bo,
    float* __restrict__ out) {
  // SMEM (bytes):
  //   [0, 32768):     K frames: buf*16384 + ks*1024 (frag-linear, +16*l)
  //   [32768, 65536): V frames: 32768 + buf*16384 + f*1024
  //   [65536, 73728): P dbuf:   65536 + pbuf*4096 + g*2048 + fr*1024 (+16*l)
  //   [73728, 74240): ML per g: g*256 + {m[32] @0, l[32] @128}  (single-buffered)
  //   [74240, 75264): AF dbuf:  74240 + pbuf*512 + g*256 + {alpha[32] @0, flag @128}
  //   epilogue reuse: [0, 33792) = O-tile [64][264] f16 (2-way banks)
  __shared__ __align__(16) char SMEM[75264];

  const int bid = blockIdx.x;
  const int lb = ((bid & 7) << 6) | (bid >> 3);   // XCD swizzle: batch -> XCD
  const int b  = lb >> 6;
  const int q0 = (lb & 63) << 6;                  // 64 q-rows per block
  const int par = (bid >> 3) & 1;                 // desync co-resident blocks
  const int tid = threadIdx.x;
  const int w  = tid >> 6, l = tid & 63, ln = l & 31, lh = l >> 5;
  const int g  = w >> 1, hv = w & 1;              // q-group, o-half

  const f16* Qb = Q  + (size_t)b * CN * CC;
  const f16* Kb = K  + (size_t)b * CN * CC;
  const f16* Vb = Vt + (size_t)b * CC * CN;

  auto kfrm = [&](int buf, int ks) -> char* { return SMEM + (buf << 14) + (ks << 10); };
  auto vfrm = [&](int buf, int f)  -> char* { return SMEM + 32768 + (buf << 14) + (f << 10); };
  auto pfrm = [&](int pb, int fr)  -> char* { return SMEM + 65536 + (pb << 12) + (g << 11) + (fr << 10); };
  float* const MLm = (float*)(SMEM + 73728 + g * 256);
  float* const MLl = MLm + 32;
  auto AFa = [&](int pb) -> float* { return (float*)(SMEM + 74240 + (pb << 9) + (g << 8)); };

  auto stageK = [&](int buf, int kv0) {
    const f16* ksrc = Kb + (size_t)(kv0 + ln) * CC + (w * 4) * 16 + 8 * lh;
    #pragma unroll
    for (int j = 0; j < 4; ++j)
      gll16(ksrc + j * 16, kfrm(buf, w * 4 + j));
  };
  auto stageV = [&](int buf, int kv0) {
    #pragma unroll
    for (int p = 0; p < 2; ++p) {
      const int f = w * 4 + 2 * p;
      const f16* vsrc = Vb + (size_t)((f >> 1) * 32 + ln) * CN + kv0 + 8 * lh;
      gll16(vsrc,      vfrm(buf, f));
      gll16(vsrc + 16, vfrm(buf, f + 1));
    }
  };

  const int qrow = q0 + 32 * g + ln;
  f16x8 qf[16];
  #pragma unroll
  for (int ks = 0; ks < 16; ++ks)
    qf[ks] = *(const f16x8*)(Qb + (size_t)qrow * CC + ks * 16 + 8 * lh);

  f32x16 oacc[4];
  #pragma unroll
  for (int ot = 0; ot < 4; ++ot)
    #pragma unroll
    for (int i = 0; i < 16; ++i) oacc[ot][i] = 0.0f;

  auto pvstep = [&](int pb) {
    const float* af = AFa(pb);
    const float flag = af[32];
    if (flag != 0.0f) {
      #pragma unroll
      for (int r = 0; r < 16; ++r) {
        const float fr = af[(r & 3) + 8 * (r >> 2) + 4 * lh];
        #pragma unroll
        for (int ot = 0; ot < 4; ++ot) oacc[ot][r] *= fr;
      }
    }
    const f16x8 pa0 = *(const f16x8*)(pfrm(pb, 0) + l * 16);
    const f16x8 pa1 = *(const f16x8*)(pfrm(pb, 1) + l * 16);
    __builtin_amdgcn_s_setprio(1);
    #pragma unroll
    for (int ot = 0; ot < 4; ++ot) {
      const int f0 = 8 * hv + 2 * ot;
      const f16x8 v0 = *(const f16x8*)(vfrm(pb, f0) + l * 16);
      oacc[ot] = MFMA32(pa0, v0, oacc[ot]);
      const f16x8 v1 = *(const f16x8*)(vfrm(pb, f0 + 1) + l * 16);
      oacc[ot] = MFMA32(pa1, v1, oacc[ot]);
    }
    __builtin_amdgcn_s_setprio(0);
  };

  stageK(0, 0);
  __syncthreads();                                // K(0) ready

  #pragma unroll 1
  for (int it = 0; it < 128; ++it) {
    const int cur = it & 1, prv = cur ^ 1;
    if (it < 127) stageK(prv, (it + 1) * 32);     // K(it+1), drained at barrier
    stageV(cur, it * 32);                         // V(it), read next iter

    const bool own = (hv == ((it + par) & 1));    // wave-uniform, desynced

    f32x16 s;
    if (own) {
      f32x16 sa, sb;
      #pragma unroll
      for (int i = 0; i < 16; ++i) { sa[i] = 0.0f; sb[i] = 0.0f; }
      __builtin_amdgcn_s_setprio(1);
      #pragma unroll
      for (int ks = 0; ks < 8; ++ks) {
        const f16x8 kf0 = *(const f16x8*)(kfrm(cur, ks) + l * 16);
        sa = MFMA32(kf0, qf[ks], sa);
        const f16x8 kf1 = *(const f16x8*)(kfrm(cur, ks + 8) + l * 16);
        sb = MFMA32(kf1, qf[ks + 8], sb);
      }
      __builtin_amdgcn_s_setprio(0);
      #pragma unroll
      for (int i = 0; i < 16; ++i) s[i] = sa[i] + sb[i];
    }

    if (it > 0) pvstep(prv);

    if (own) {
      const float mprev = it ? MLm[ln] : -3e38f;
      const float lprev = it ? MLl[ln] : 0.0f;
      float mx8[8], mx4[4];
      #pragma unroll
      for (int i = 0; i < 8; ++i) mx8[i] = fmaxf(s[2 * i], s[2 * i + 1]);
      #pragma unroll
      for (int i = 0; i < 4; ++i) mx4[i] = fmaxf(mx8[2 * i], mx8[2 * i + 1]);
      float pmax = fmaxf(fmaxf(mx4[0], mx4[1]), fmaxf(mx4[2], mx4[3]));
      pmax = fmaxf(pmax, __shfl_xor(pmax, 32));
      const bool need = !__all(pmax - mprev <= 8.0f);   // defer-max (T13)
      const float mnew = need ? fmaxf(mprev, pmax) : mprev;
      float p[16];
      #pragma unroll
      for (int r = 0; r < 16; ++r) p[r] = __expf(s[r] - mnew);
      float sm8[8], sm4[4];
      #pragma unroll
      for (int i = 0; i < 8; ++i) sm8[i] = p[2 * i] + p[2 * i + 1];
      #pragma unroll
      for (int i = 0; i < 4; ++i) sm4[i] = sm8[2 * i] + sm8[2 * i + 1];
      float psum = (sm4[0] + sm4[1]) + (sm4[2] + sm4[3]);
      psum += __shfl_xor(psum, 32);
      float alpha = 1.0f, lnew;
      if (need) { alpha = __expf(mprev - mnew); lnew = lprev * alpha + psum; }
      else      { lnew = lprev + psum; }
      if (l < 32) {
        MLm[ln] = mnew;
        MLl[ln] = lnew;
        float* af = AFa(cur);
        af[ln] = alpha;
        if (ln == 0) af[32] = need ? 1.0f : 0.0f;
      }
      u32 pw[8];
      #pragma unroll
      for (int i = 0; i < 8; ++i) pw[i] = pk(p[2 * i], p[2 * i + 1]);
      plswap(pw[0], pw[2]); plswap(pw[1], pw[3]);
      plswap(pw[4], pw[6]); plswap(pw[5], pw[7]);
      *(u32x4*)(pfrm(cur, 0) + l * 16) = u32x4{pw[0], pw[1], pw[2], pw[3]};
      *(u32x4*)(pfrm(cur, 1) + l * 16) = u32x4{pw[4], pw[5], pw[6], pw[7]};
    }
    __syncthreads();   // drains K(it+1)/V(it); publishes P/ML/AF(it)
  }

  // epilogue part 1: PV(127) (buffers pb=1), grab 1/l values
  pvstep(1);
  float invv[16];
  #pragma unroll
  for (int r = 0; r < 16; ++r)
    invv[r] = 1.0f / MLl[(r & 3) + 8 * (r >> 2) + 4 * lh];
  __syncthreads();                                // everyone done with K/ML regions

  // epilogue part 2: normalized O-tile -> LDS [64][264] f16
  f16* const OT = (f16*)SMEM;
  #pragma unroll
  for (int r = 0; r < 16; ++r) {
    const int q = (r & 3) + 8 * (r >> 2) + 4 * lh;
    const int qq = 32 * g + q;
    #pragma unroll
    for (int ot = 0; ot < 4; ++ot)
      OT[qq * 264 + 128 * hv + ot * 32 + ln] = (f16)(oacc[ot][r] * invv[r]);
  }
  __syncthreads();

  // epilogue part 3: fused out-projection (verified oproj body, bf from LDS)
  {
    const int lr = l & 15, lq = l >> 4;           // 16x4 lane split
    const f16* orow = OT + (w * 16 + lr) * 264;
    f32x4 acc[16];
    #pragma unroll
    for (int m = 0; m < 16; ++m) acc[m] = f32x4{0.f, 0.f, 0.f, 0.f};
    #pragma unroll
    for (int kk = 0; kk < 8; ++kk) {
      const f16x8 bf = *(const f16x8*)&orow[kk * 32 + lq * 8];
      #pragma unroll
      for (int m = 0; m < 16; ++m) {
        f16x8 af = *(const f16x8*)&Wo[(size_t)(m * 16 + lr) * CC + kk * 32 + lq * 8];
        acc[m] = MFMA(af, bf, acc[m]);
      }
    }
    #pragma unroll
    for (int m = 0; m < 16; ++m) {
      const int c = m * 16 + lq * 4;
      const float4 bv4 = *(const float4*)&bo[c];
      const size_t base = ((size_t)b * CC + c) * CN + q0 + w * 16 + lr;
      out[base + 0 * (size_t)CN] = acc[m][0] + bv4.x;
      out[base + 1 * (size_t)CN] = acc[m][1] + bv4.y;
      out[base + 2 * (size_t)CN] = acc[m][2] + bv4.z;
      out[base + 3 * (size_t)CN] = acc[m][3] + bv4.w;
    }
  }
}

extern "C" void kernel_launch(void* const* d_in, const int* in_sizes, int n_in,
                              void* d_out, int out_size, void* d_ws, size_t ws_size,
                              hipStream_t stream) {
  const float* x  = (const float*)d_in[0];
  const float* wq = (const float*)d_in[1];
  const float* bq = (const float*)d_in[2];
  const float* wk = (const float*)d_in[3];
  const float* bk = (const float*)d_in[4];
  const float* wv = (const float*)d_in[5];
  const float* bv = (const float*)d_in[6];
  const float* wo = (const float*)d_in[7];
  const float* bo = (const float*)d_in[8];

  f16* W  = (f16*)d_ws;                     // 4 x 65536 f16 weights
  f16* Qd = W + 262144;                     // [B,N,256]
  f16* Kd = Qd + (size_t)CB * CN * CC;      // [B,N,256]
  f16* Vt = Kd + (size_t)CB * CN * CC;      // [B,256,N]

  prep_weights<<<256, 256, 0, stream>>>(wq, wk, wv, wo, W);
  qkv_kernel<<<1024, 256, 0, stream>>>(x, W, W + 65536, W + 131072, bq, bk, bv, Qd, Kd, Vt);
  attn_kernel<<<512, 256, 0, stream>>>(Qd, Kd, Vt, W + 196608, bo, (float*)d_out);
}

// Round 14
// 336.662 us; speedup vs baseline: 2.6278x; 1.1224x over previous
//
#include <hip/hip_runtime.h>
#include <hip/hip_fp16.h>

typedef _Float16 f16;
typedef _Float16 f16x4 __attribute__((ext_vector_type(4)));
typedef _Float16 f16x8 __attribute__((ext_vector_type(8)));
typedef float f32x4 __attribute__((ext_vector_type(4)));
typedef float f32x16 __attribute__((ext_vector_type(16)));
typedef unsigned int u32;
typedef u32 u32x4 __attribute__((ext_vector_type(4)));

static constexpr int CB = 8;      // batch
static constexpr int CC = 256;    // channels = Co
static constexpr int CN = 4096;   // tokens = H*W

#define MFMA(a, b, c)   __builtin_amdgcn_mfma_f32_16x16x32_f16((a), (b), (c), 0, 0, 0)
#define MFMA32(a, b, c) __builtin_amdgcn_mfma_f32_32x32x16_f16((a), (b), (c), 0, 0, 0)

__device__ __forceinline__ void gll16(const void* g, void* l) {
  __builtin_amdgcn_global_load_lds(
      (const __attribute__((address_space(1))) unsigned int*)g,
      (__attribute__((address_space(3))) unsigned int*)l, 16, 0, 0);
}

// swap a's lanes 32-63 with b's lanes 0-31 (CDNA4 cross-half exchange)
__device__ __forceinline__ void plswap(u32& a, u32& b) {
  asm volatile("v_permlane32_swap_b32 %0, %1" : "+v"(a), "+v"(b));
}

__device__ __forceinline__ u32 pk(float lo, float hi) {
  auto h = __builtin_amdgcn_cvt_pkrtz(lo, hi);   // __fp16 ext_vector_type(2)
  return __builtin_bit_cast(u32, h);
}

__global__ __launch_bounds__(256) void prep_weights(const float* __restrict__ wq,
    const float* __restrict__ wk, const float* __restrict__ wv,
    const float* __restrict__ wo, f16* __restrict__ W) {
  int i = blockIdx.x * 256 + threadIdx.x;
  W[i]          = (f16)wq[i];
  W[65536 + i]  = (f16)wk[i];
  W[131072 + i] = (f16)wv[i];
  W[196608 + i] = (f16)wo[i];
}

// qkv v3: 32x32x16 MFMA, 32 n-rows per wave -> each weight-fragment read feeds
// 2x output (L2 weight traffic halves vs 16-row waves). 128-thr blocks (2 waves),
// grid 512, x-tile [64][264] LDS. Q/K: D[o][n]=mfma(W,x); V: D[n][o]=mfma(x,W).
__global__ __launch_bounds__(128) void qkv_kernel(const float* __restrict__ x,
    const f16* __restrict__ Wq, const f16* __restrict__ Wk, const f16* __restrict__ Wv,
    const float* __restrict__ bq, const float* __restrict__ bk, const float* __restrict__ bv,
    f16* __restrict__ Q, f16* __restrict__ K, f16* __restrict__ Vt) {
  __shared__ f16 xf[64][264];
  const int b  = blockIdx.x >> 6;
  const int n0 = (blockIdx.x & 63) << 6;
  const int t  = threadIdx.x;
  const float* xb = x + (size_t)b * CC * CN;
  {
    int c = t >> 4;                         // 0..7
    const int nn = (t & 15) << 2;
    #pragma unroll
    for (int pass = 0; pass < 32; ++pass, c += 8) {
      const float4 v = *(const float4*)(xb + (size_t)c * CN + n0 + nn);
      xf[nn + 0][c] = (f16)v.x;
      xf[nn + 1][c] = (f16)v.y;
      xf[nn + 2][c] = (f16)v.z;
      xf[nn + 3][c] = (f16)v.w;
    }
  }
  __syncthreads();
  const int w = t >> 6, l = t & 63, ln = l & 31, lh = l >> 5;

  // B-fragment of 32x32x16: lane row = ln (n), k = kt*16 + 8*lh + e
  f16x8 xff[16];
  #pragma unroll
  for (int kt = 0; kt < 16; ++kt)
    xff[kt] = *(const f16x8*)&xf[w * 32 + ln][kt * 16 + lh * 8];

  const size_t qkrow = ((size_t)b * CN + n0 + w * 32 + ln) * CC;

  // Q and K: D[o][n] = mfma(A=W(o,c), B=x(n,c)); lane n = ln,
  // o = ot*32 + 8*rg + 4*lh + j  (reg r = 4*rg + j)
  #pragma unroll 1
  for (int mat = 0; mat < 2; ++mat) {
    const f16* W = mat ? Wk : Wq;
    const float* bias = mat ? bk : bq;
    f16* dst = mat ? K : Q;
    #pragma unroll 1
    for (int ot = 0; ot < 8; ot += 2) {
      f32x16 a0, a1;
      #pragma unroll
      for (int i = 0; i < 16; ++i) { a0[i] = 0.0f; a1[i] = 0.0f; }
      #pragma unroll
      for (int kt = 0; kt < 16; ++kt) {
        const f16x8 af0 = *(const f16x8*)&W[(size_t)(ot * 32 + ln) * CC + kt * 16 + lh * 8];
        a0 = MFMA32(af0, xff[kt], a0);
        const f16x8 af1 = *(const f16x8*)&W[(size_t)(ot * 32 + 32 + ln) * CC + kt * 16 + lh * 8];
        a1 = MFMA32(af1, xff[kt], a1);
      }
      #pragma unroll
      for (int rg = 0; rg < 4; ++rg) {
        const int o = ot * 32 + rg * 8 + lh * 4;
        const float4 b0 = *(const float4*)&bias[o];
        const float4 b1 = *(const float4*)&bias[o + 32];
        f16x4 h0, h1;
        h0[0] = (f16)(a0[rg * 4 + 0] + b0.x);
        h0[1] = (f16)(a0[rg * 4 + 1] + b0.y);
        h0[2] = (f16)(a0[rg * 4 + 2] + b0.z);
        h0[3] = (f16)(a0[rg * 4 + 3] + b0.w);
        h1[0] = (f16)(a1[rg * 4 + 0] + b1.x);
        h1[1] = (f16)(a1[rg * 4 + 1] + b1.y);
        h1[2] = (f16)(a1[rg * 4 + 2] + b1.z);
        h1[3] = (f16)(a1[rg * 4 + 3] + b1.w);
        *(f16x4*)&dst[qkrow + o]      = h0;
        *(f16x4*)&dst[qkrow + o + 32] = h1;
      }
    }
  }

  // V: D[n][o] = mfma(A=x(n,c), B=W(o,c)); lane o = ot*32 + ln,
  // n = 8*rg + 4*lh + j -> contiguous f16x4 into V^T rows
  #pragma unroll 1
  for (int ot = 0; ot < 8; ot += 2) {
    f32x16 a0, a1;
    #pragma unroll
    for (int i = 0; i < 16; ++i) { a0[i] = 0.0f; a1[i] = 0.0f; }
    #pragma unroll
    for (int kt = 0; kt < 16; ++kt) {
      const f16x8 wf0 = *(const f16x8*)&Wv[(size_t)(ot * 32 + ln) * CC + kt * 16 + lh * 8];
      a0 = MFMA32(xff[kt], wf0, a0);
      const f16x8 wf1 = *(const f16x8*)&Wv[(size_t)(ot * 32 + 32 + ln) * CC + kt * 16 + lh * 8];
      a1 = MFMA32(xff[kt], wf1, a1);
    }
    const int o0 = ot * 32 + ln, o1 = o0 + 32;
    const float bv0 = bv[o0], bv1 = bv[o1];
    f16* v0 = &Vt[((size_t)b * CC + o0) * CN + n0 + w * 32];
    f16* v1 = &Vt[((size_t)b * CC + o1) * CN + n0 + w * 32];
    #pragma unroll
    for (int rg = 0; rg < 4; ++rg) {
      const int nn = rg * 8 + lh * 4;
      f16x4 h0, h1;
      #pragma unroll
      for (int j = 0; j < 4; ++j) {
        h0[j] = (f16)(a0[rg * 4 + j] + bv0);
        h1[j] = (f16)(a1[rg * 4 + j] + bv1);
      }
      *(f16x4*)&v0[nn] = h0;
      *(f16x4*)&v1[nn] = h1;
    }
  }
}

// flash attention v12 (unchanged, verified): P-exchange dedup + desync + dual QK
// chains + fused out-projection. Q,K [B,N,256], V^T [B,256,N], Wo -> out [B,C,N]
__global__ __launch_bounds__(256, 2) void attn_kernel(const f16* __restrict__ Q,
    const f16* __restrict__ K, const f16* __restrict__ Vt,
    const f16* __restrict__ Wo, const float* __restrict__ bo,
    float* __restrict__ out) {
  // SMEM (bytes):
  //   [0, 32768):     K frames: buf*16384 + ks*1024 (frag-linear, +16*l)
  //   [32768, 65536): V frames: 32768 + buf*16384 + f*1024
  //   [65536, 73728): P dbuf:   65536 + pbuf*4096 + g*2048 + fr*1024 (+16*l)
  //   [73728, 74240): ML per g: g*256 + {m[32] @0, l[32] @128}  (single-buffered)
  //   [74240, 75264): AF dbuf:  74240 + pbuf*512 + g*256 + {alpha[32] @0, flag @128}
  //   epilogue reuse: [0, 33792) = O-tile [64][264] f16 (2-way banks)
  __shared__ __align__(16) char SMEM[75264];

  const int bid = blockIdx.x;
  const int lb = ((bid & 7) << 6) | (bid >> 3);   // XCD swizzle: batch -> XCD
  const int b  = lb >> 6;
  const int q0 = (lb & 63) << 6;                  // 64 q-rows per block
  const int par = (bid >> 3) & 1;                 // desync co-resident blocks
  const int tid = threadIdx.x;
  const int w  = tid >> 6, l = tid & 63, ln = l & 31, lh = l >> 5;
  const int g  = w >> 1, hv = w & 1;              // q-group, o-half

  const f16* Qb = Q  + (size_t)b * CN * CC;
  const f16* Kb = K  + (size_t)b * CN * CC;
  const f16* Vb = Vt + (size_t)b * CC * CN;

  auto kfrm = [&](int buf, int ks) -> char* { return SMEM + (buf << 14) + (ks << 10); };
  auto vfrm = [&](int buf, int f)  -> char* { return SMEM + 32768 + (buf << 14) + (f << 10); };
  auto pfrm = [&](int pb, int fr)  -> char* { return SMEM + 65536 + (pb << 12) + (g << 11) + (fr << 10); };
  float* const MLm = (float*)(SMEM + 73728 + g * 256);
  float* const MLl = MLm + 32;
  auto AFa = [&](int pb) -> float* { return (float*)(SMEM + 74240 + (pb << 9) + (g << 8)); };

  auto stageK = [&](int buf, int kv0) {
    const f16* ksrc = Kb + (size_t)(kv0 + ln) * CC + (w * 4) * 16 + 8 * lh;
    #pragma unroll
    for (int j = 0; j < 4; ++j)
      gll16(ksrc + j * 16, kfrm(buf, w * 4 + j));
  };
  auto stageV = [&](int buf, int kv0) {
    #pragma unroll
    for (int p = 0; p < 2; ++p) {
      const int f = w * 4 + 2 * p;
      const f16* vsrc = Vb + (size_t)((f >> 1) * 32 + ln) * CN + kv0 + 8 * lh;
      gll16(vsrc,      vfrm(buf, f));
      gll16(vsrc + 16, vfrm(buf, f + 1));
    }
  };

  const int qrow = q0 + 32 * g + ln;
  f16x8 qf[16];
  #pragma unroll
  for (int ks = 0; ks < 16; ++ks)
    qf[ks] = *(const f16x8*)(Qb + (size_t)qrow * CC + ks * 16 + 8 * lh);

  f32x16 oacc[4];
  #pragma unroll
  for (int ot = 0; ot < 4; ++ot)
    #pragma unroll
    for (int i = 0; i < 16; ++i) oacc[ot][i] = 0.0f;

  auto pvstep = [&](int pb) {
    const float* af = AFa(pb);
    const float flag = af[32];
    if (flag != 0.0f) {
      #pragma unroll
      for (int r = 0; r < 16; ++r) {
        const float fr = af[(r & 3) + 8 * (r >> 2) + 4 * lh];
        #pragma unroll
        for (int ot = 0; ot < 4; ++ot) oacc[ot][r] *= fr;
      }
    }
    const f16x8 pa0 = *(const f16x8*)(pfrm(pb, 0) + l * 16);
    const f16x8 pa1 = *(const f16x8*)(pfrm(pb, 1) + l * 16);
    __builtin_amdgcn_s_setprio(1);
    #pragma unroll
    for (int ot = 0; ot < 4; ++ot) {
      const int f0 = 8 * hv + 2 * ot;
      const f16x8 v0 = *(const f16x8*)(vfrm(pb, f0) + l * 16);
      oacc[ot] = MFMA32(pa0, v0, oacc[ot]);
      const f16x8 v1 = *(const f16x8*)(vfrm(pb, f0 + 1) + l * 16);
      oacc[ot] = MFMA32(pa1, v1, oacc[ot]);
    }
    __builtin_amdgcn_s_setprio(0);
  };

  stageK(0, 0);
  __syncthreads();                                // K(0) ready

  #pragma unroll 1
  for (int it = 0; it < 128; ++it) {
    const int cur = it & 1, prv = cur ^ 1;
    if (it < 127) stageK(prv, (it + 1) * 32);     // K(it+1), drained at barrier
    stageV(cur, it * 32);                         // V(it), read next iter

    const bool own = (hv == ((it + par) & 1));    // wave-uniform, desynced

    f32x16 s;
    if (own) {
      f32x16 sa, sb;
      #pragma unroll
      for (int i = 0; i < 16; ++i) { sa[i] = 0.0f; sb[i] = 0.0f; }
      __builtin_amdgcn_s_setprio(1);
      #pragma unroll
      for (int ks = 0; ks < 8; ++ks) {
        const f16x8 kf0 = *(const f16x8*)(kfrm(cur, ks) + l * 16);
        sa = MFMA32(kf0, qf[ks], sa);
        const f16x8 kf1 = *(const f16x8*)(kfrm(cur, ks + 8) + l * 16);
        sb = MFMA32(kf1, qf[ks + 8], sb);
      }
      __builtin_amdgcn_s_setprio(0);
      #pragma unroll
      for (int i = 0; i < 16; ++i) s[i] = sa[i] + sb[i];
    }

    if (it > 0) pvstep(prv);

    if (own) {
      const float mprev = it ? MLm[ln] : -3e38f;
      const float lprev = it ? MLl[ln] : 0.0f;
      float mx8[8], mx4[4];
      #pragma unroll
      for (int i = 0; i < 8; ++i) mx8[i] = fmaxf(s[2 * i], s[2 * i + 1]);
      #pragma unroll
      for (int i = 0; i < 4; ++i) mx4[i] = fmaxf(mx8[2 * i], mx8[2 * i + 1]);
      float pmax = fmaxf(fmaxf(mx4[0], mx4[1]), fmaxf(mx4[2], mx4[3]));
      pmax = fmaxf(pmax, __shfl_xor(pmax, 32));
      const bool need = !__all(pmax - mprev <= 8.0f);   // defer-max (T13)
      const float mnew = need ? fmaxf(mprev, pmax) : mprev;
      float p[16];
      #pragma unroll
      for (int r = 0; r < 16; ++r) p[r] = __expf(s[r] - mnew);
      float sm8[8], sm4[4];
      #pragma unroll
      for (int i = 0; i < 8; ++i) sm8[i] = p[2 * i] + p[2 * i + 1];
      #pragma unroll
      for (int i = 0; i < 4; ++i) sm4[i] = sm8[2 * i] + sm8[2 * i + 1];
      float psum = (sm4[0] + sm4[1]) + (sm4[2] + sm4[3]);
      psum += __shfl_xor(psum, 32);
      float alpha = 1.0f, lnew;
      if (need) { alpha = __expf(mprev - mnew); lnew = lprev * alpha + psum; }
      else      { lnew = lprev + psum; }
      if (l < 32) {
        MLm[ln] = mnew;
        MLl[ln] = lnew;
        float* af = AFa(cur);
        af[ln] = alpha;
        if (ln == 0) af[32] = need ? 1.0f : 0.0f;
      }
      u32 pw[8];
      #pragma unroll
      for (int i = 0; i < 8; ++i) pw[i] = pk(p[2 * i], p[2 * i + 1]);
      plswap(pw[0], pw[2]); plswap(pw[1], pw[3]);
      plswap(pw[4], pw[6]); plswap(pw[5], pw[7]);
      *(u32x4*)(pfrm(cur, 0) + l * 16) = u32x4{pw[0], pw[1], pw[2], pw[3]};
      *(u32x4*)(pfrm(cur, 1) + l * 16) = u32x4{pw[4], pw[5], pw[6], pw[7]};
    }
    __syncthreads();   // drains K(it+1)/V(it); publishes P/ML/AF(it)
  }

  // epilogue part 1: PV(127) (buffers pb=1), grab 1/l values
  pvstep(1);
  float invv[16];
  #pragma unroll
  for (int r = 0; r < 16; ++r)
    invv[r] = 1.0f / MLl[(r & 3) + 8 * (r >> 2) + 4 * lh];
  __syncthreads();                                // everyone done with K/ML regions

  // epilogue part 2: normalized O-tile -> LDS [64][264] f16
  f16* const OT = (f16*)SMEM;
  #pragma unroll
  for (int r = 0; r < 16; ++r) {
    const int q = (r & 3) + 8 * (r >> 2) + 4 * lh;
    const int qq = 32 * g + q;
    #pragma unroll
    for (int ot = 0; ot < 4; ++ot)
      OT[qq * 264 + 128 * hv + ot * 32 + ln] = (f16)(oacc[ot][r] * invv[r]);
  }
  __syncthreads();

  // epilogue part 3: fused out-projection (verified oproj body, bf from LDS)
  {
    const int lr = l & 15, lq = l >> 4;           // 16x4 lane split
    const f16* orow = OT + (w * 16 + lr) * 264;
    f32x4 acc[16];
    #pragma unroll
    for (int m = 0; m < 16; ++m) acc[m] = f32x4{0.f, 0.f, 0.f, 0.f};
    #pragma unroll
    for (int kk = 0; kk < 8; ++kk) {
      const f16x8 bf = *(const f16x8*)&orow[kk * 32 + lq * 8];
      #pragma unroll
      for (int m = 0; m < 16; ++m) {
        f16x8 af = *(const f16x8*)&Wo[(size_t)(m * 16 + lr) * CC + kk * 32 + lq * 8];
        acc[m] = MFMA(af, bf, acc[m]);
      }
    }
    #pragma unroll
    for (int m = 0; m < 16; ++m) {
      const int c = m * 16 + lq * 4;
      const float4 bv4 = *(const float4*)&bo[c];
      const size_t base = ((size_t)b * CC + c) * CN + q0 + w * 16 + lr;
      out[base + 0 * (size_t)CN] = acc[m][0] + bv4.x;
      out[base + 1 * (size_t)CN] = acc[m][1] + bv4.y;
      out[base + 2 * (size_t)CN] = acc[m][2] + bv4.z;
      out[base + 3 * (size_t)CN] = acc[m][3] + bv4.w;
    }
  }
}

extern "C" void kernel_launch(void* const* d_in, const int* in_sizes, int n_in,
                              void* d_out, int out_size, void* d_ws, size_t ws_size,
                              hipStream_t stream) {
  const float* x  = (const float*)d_in[0];
  const float* wq = (const float*)d_in[1];
  const float* bq = (const float*)d_in[2];
  const float* wk = (const float*)d_in[3];
  const float* bk = (const float*)d_in[4];
  const float* wv = (const float*)d_in[5];
  const float* bv = (const float*)d_in[6];
  const float* wo = (const float*)d_in[7];
  const float* bo = (const float*)d_in[8];

  f16* W  = (f16*)d_ws;                     // 4 x 65536 f16 weights
  f16* Qd = W + 262144;                     // [B,N,256]
  f16* Kd = Qd + (size_t)CB * CN * CC;      // [B,N,256]
  f16* Vt = Kd + (size_t)CB * CN * CC;      // [B,256,N]

  prep_weights<<<256, 256, 0, stream>>>(wq, wk, wv, wo, W);
  qkv_kernel<<<512, 128, 0, stream>>>(x, W, W + 65536, W + 131072, bq, bk, bv, Qd, Kd, Vt);
  attn_kernel<<<512, 256, 0, stream>>>(Qd, Kd, Vt, W + 196608, bo, (float*)d_out);
}

// Round 16
// 336.604 us; speedup vs baseline: 2.6283x; 1.0002x over previous
//
#include <hip/hip_runtime.h>
#include <hip/hip_fp16.h>

typedef _Float16 f16;
typedef _Float16 f16x4 __attribute__((ext_vector_type(4)));
typedef _Float16 f16x8 __attribute__((ext_vector_type(8)));
typedef float f32x4 __attribute__((ext_vector_type(4)));
typedef float f32x16 __attribute__((ext_vector_type(16)));
typedef unsigned int u32;
typedef u32 u32x4 __attribute__((ext_vector_type(4)));

static constexpr int CB = 8;      // batch
static constexpr int CC = 256;    // channels = Co
static constexpr int CN = 4096;   // tokens = H*W

#define MFMA(a, b, c)   __builtin_amdgcn_mfma_f32_16x16x32_f16((a), (b), (c), 0, 0, 0)
#define MFMA32(a, b, c) __builtin_amdgcn_mfma_f32_32x32x16_f16((a), (b), (c), 0, 0, 0)

__device__ __forceinline__ void gll16(const void* g, void* l) {
  __builtin_amdgcn_global_load_lds(
      (const __attribute__((address_space(1))) unsigned int*)g,
      (__attribute__((address_space(3))) unsigned int*)l, 16, 0, 0);
}

// swap a's lanes 32-63 with b's lanes 0-31 (CDNA4 cross-half exchange)
__device__ __forceinline__ void plswap(u32& a, u32& b) {
  asm volatile("v_permlane32_swap_b32 %0, %1" : "+v"(a), "+v"(b));
}

__device__ __forceinline__ u32 pk(float lo, float hi) {
  auto h = __builtin_amdgcn_cvt_pkrtz(lo, hi);   // __fp16 ext_vector_type(2)
  return __builtin_bit_cast(u32, h);
}

__device__ __forceinline__ float f3(float a, float b, float c) {   // fuses to v_max3_f32
  return fmaxf(fmaxf(a, b), c);
}

__global__ __launch_bounds__(256) void prep_weights(const float* __restrict__ wq,
    const float* __restrict__ wk, const float* __restrict__ wv,
    const float* __restrict__ wo, f16* __restrict__ W) {
  int i = blockIdx.x * 256 + threadIdx.x;
  W[i]          = (f16)wq[i];
  W[65536 + i]  = (f16)wk[i];
  W[131072 + i] = (f16)wv[i];
  W[196608 + i] = (f16)wo[i];
}

// qkv v3 (verified): 32x32x16 MFMA, 32 n-rows per wave -> weight L2 traffic
// halves vs 16-row waves. Q/K: D[o][n]=mfma(W,x); V: D[n][o]=mfma(x,W).
__global__ __launch_bounds__(128) void qkv_kernel(const float* __restrict__ x,
    const f16* __restrict__ Wq, const f16* __restrict__ Wk, const f16* __restrict__ Wv,
    const float* __restrict__ bq, const float* __restrict__ bk, const float* __restrict__ bv,
    f16* __restrict__ Q, f16* __restrict__ K, f16* __restrict__ Vt) {
  __shared__ f16 xf[64][264];
  const int b  = blockIdx.x >> 6;
  const int n0 = (blockIdx.x & 63) << 6;
  const int t  = threadIdx.x;
  const float* xb = x + (size_t)b * CC * CN;
  {
    int c = t >> 4;                         // 0..7
    const int nn = (t & 15) << 2;
    #pragma unroll
    for (int pass = 0; pass < 32; ++pass, c += 8) {
      const float4 v = *(const float4*)(xb + (size_t)c * CN + n0 + nn);
      xf[nn + 0][c] = (f16)v.x;
      xf[nn + 1][c] = (f16)v.y;
      xf[nn + 2][c] = (f16)v.z;
      xf[nn + 3][c] = (f16)v.w;
    }
  }
  __syncthreads();
  const int w = t >> 6, l = t & 63, ln = l & 31, lh = l >> 5;

  // B-fragment of 32x32x16: lane row = ln (n), k = kt*16 + 8*lh + e
  f16x8 xff[16];
  #pragma unroll
  for (int kt = 0; kt < 16; ++kt)
    xff[kt] = *(const f16x8*)&xf[w * 32 + ln][kt * 16 + lh * 8];

  const size_t qkrow = ((size_t)b * CN + n0 + w * 32 + ln) * CC;

  #pragma unroll 1
  for (int mat = 0; mat < 2; ++mat) {
    const f16* W = mat ? Wk : Wq;
    const float* bias = mat ? bk : bq;
    f16* dst = mat ? K : Q;
    #pragma unroll 1
    for (int ot = 0; ot < 8; ot += 2) {
      f32x16 a0, a1;
      #pragma unroll
      for (int i = 0; i < 16; ++i) { a0[i] = 0.0f; a1[i] = 0.0f; }
      #pragma unroll
      for (int kt = 0; kt < 16; ++kt) {
        const f16x8 af0 = *(const f16x8*)&W[(size_t)(ot * 32 + ln) * CC + kt * 16 + lh * 8];
        a0 = MFMA32(af0, xff[kt], a0);
        const f16x8 af1 = *(const f16x8*)&W[(size_t)(ot * 32 + 32 + ln) * CC + kt * 16 + lh * 8];
        a1 = MFMA32(af1, xff[kt], a1);
      }
      #pragma unroll
      for (int rg = 0; rg < 4; ++rg) {
        const int o = ot * 32 + rg * 8 + lh * 4;
        const float4 b0 = *(const float4*)&bias[o];
        const float4 b1 = *(const float4*)&bias[o + 32];
        f16x4 h0, h1;
        h0[0] = (f16)(a0[rg * 4 + 0] + b0.x);
        h0[1] = (f16)(a0[rg * 4 + 1] + b0.y);
        h0[2] = (f16)(a0[rg * 4 + 2] + b0.z);
        h0[3] = (f16)(a0[rg * 4 + 3] + b0.w);
        h1[0] = (f16)(a1[rg * 4 + 0] + b1.x);
        h1[1] = (f16)(a1[rg * 4 + 1] + b1.y);
        h1[2] = (f16)(a1[rg * 4 + 2] + b1.z);
        h1[3] = (f16)(a1[rg * 4 + 3] + b1.w);
        *(f16x4*)&dst[qkrow + o]      = h0;
        *(f16x4*)&dst[qkrow + o + 32] = h1;
      }
    }
  }

  #pragma unroll 1
  for (int ot = 0; ot < 8; ot += 2) {
    f32x16 a0, a1;
    #pragma unroll
    for (int i = 0; i < 16; ++i) { a0[i] = 0.0f; a1[i] = 0.0f; }
    #pragma unroll
    for (int kt = 0; kt < 16; ++kt) {
      const f16x8 wf0 = *(const f16x8*)&Wv[(size_t)(ot * 32 + ln) * CC + kt * 16 + lh * 8];
      a0 = MFMA32(xff[kt], wf0, a0);
      const f16x8 wf1 = *(const f16x8*)&Wv[(size_t)(ot * 32 + 32 + ln) * CC + kt * 16 + lh * 8];
      a1 = MFMA32(xff[kt], wf1, a1);
    }
    const int o0 = ot * 32 + ln, o1 = o0 + 32;
    const float bv0 = bv[o0], bv1 = bv[o1];
    f16* v0 = &Vt[((size_t)b * CC + o0) * CN + n0 + w * 32];
    f16* v1 = &Vt[((size_t)b * CC + o1) * CN + n0 + w * 32];
    #pragma unroll
    for (int rg = 0; rg < 4; ++rg) {
      const int nn = rg * 8 + lh * 4;
      f16x4 h0, h1;
      #pragma unroll
      for (int j = 0; j < 4; ++j) {
        h0[j] = (f16)(a0[rg * 4 + j] + bv0);
        h1[j] = (f16)(a1[rg * 4 + j] + bv1);
      }
      *(f16x4*)&v0[nn] = h0;
      *(f16x4*)&v1[nn] = h1;
    }
  }
}

// flash attention v12r: P-exchange dedup + desync + dual QK chains + fused
// out-projection (verified structure) + max3 pmax tree + owner-prio span.
__global__ __launch_bounds__(256, 2) void attn_kernel(const f16* __restrict__ Q,
    const f16* __restrict__ K, const f16* __restrict__ Vt,
    const f16* __restrict__ Wo, const float* __restrict__ bo,
    float* __restrict__ out) {
  // SMEM (bytes):
  //   [0, 32768):     K frames: buf*16384 + ks*1024 (frag-linear, +16*l)
  //   [32768, 65536): V frames: 32768 + buf*16384 + f*1024
  //   [65536, 73728): P dbuf:   65536 + pbuf*4096 + g*2048 + fr*1024 (+16*l)
  //   [73728, 74240): ML per g: g*256 + {m[32] @0, l[32] @128}  (single-buffered)
  //   [74240, 75264): AF dbuf:  74240 + pbuf*512 + g*256 + {alpha[32] @0, flag @128}
  //   epilogue reuse: [0, 33792) = O-tile [64][264] f16 (2-way banks)
  __shared__ __align__(16) char SMEM[75264];

  const int bid = blockIdx.x;
  const int lb = ((bid & 7) << 6) | (bid >> 3);   // XCD swizzle: batch -> XCD
  const int b  = lb >> 6;
  const int q0 = (lb & 63) << 6;                  // 64 q-rows per block
  const int par = (bid >> 3) & 1;                 // desync co-resident blocks
  const int tid = threadIdx.x;
  const int w  = tid >> 6, l = tid & 63, ln = l & 31, lh = l >> 5;
  const int g  = w >> 1, hv = w & 1;              // q-group, o-half

  const f16* Qb = Q  + (size_t)b * CN * CC;
  const f16* Kb = K  + (size_t)b * CN * CC;
  const f16* Vb = Vt + (size_t)b * CC * CN;

  auto kfrm = [&](int buf, int ks) -> char* { return SMEM + (buf << 14) + (ks << 10); };
  auto vfrm = [&](int buf, int f)  -> char* { return SMEM + 32768 + (buf << 14) + (f << 10); };
  auto pfrm = [&](int pb, int fr)  -> char* { return SMEM + 65536 + (pb << 12) + (g << 11) + (fr << 10); };
  float* const MLm = (float*)(SMEM + 73728 + g * 256);
  float* const MLl = MLm + 32;
  auto AFa = [&](int pb) -> float* { return (float*)(SMEM + 74240 + (pb << 9) + (g << 8)); };

  auto stageK = [&](int buf, int kv0) {
    const f16* ksrc = Kb + (size_t)(kv0 + ln) * CC + (w * 4) * 16 + 8 * lh;
    #pragma unroll
    for (int j = 0; j < 4; ++j)
      gll16(ksrc + j * 16, kfrm(buf, w * 4 + j));
  };
  auto stageV = [&](int buf, int kv0) {
    #pragma unroll
    for (int p = 0; p < 2; ++p) {
      const int f = w * 4 + 2 * p;
      const f16* vsrc = Vb + (size_t)((f >> 1) * 32 + ln) * CN + kv0 + 8 * lh;
      gll16(vsrc,      vfrm(buf, f));
      gll16(vsrc + 16, vfrm(buf, f + 1));
    }
  };

  const int qrow = q0 + 32 * g + ln;
  f16x8 qf[16];
  #pragma unroll
  for (int ks = 0; ks < 16; ++ks)
    qf[ks] = *(const f16x8*)(Qb + (size_t)qrow * CC + ks * 16 + 8 * lh);

  f32x16 oacc[4];
  #pragma unroll
  for (int ot = 0; ot < 4; ++ot)
    #pragma unroll
    for (int i = 0; i < 16; ++i) oacc[ot][i] = 0.0f;

  auto pvstep = [&](int pb) {
    const float* af = AFa(pb);
    const float flag = af[32];
    if (flag != 0.0f) {
      #pragma unroll
      for (int r = 0; r < 16; ++r) {
        const float fr = af[(r & 3) + 8 * (r >> 2) + 4 * lh];
        #pragma unroll
        for (int ot = 0; ot < 4; ++ot) oacc[ot][r] *= fr;
      }
    }
    const f16x8 pa0 = *(const f16x8*)(pfrm(pb, 0) + l * 16);
    const f16x8 pa1 = *(const f16x8*)(pfrm(pb, 1) + l * 16);
    __builtin_amdgcn_s_setprio(1);
    #pragma unroll
    for (int ot = 0; ot < 4; ++ot) {
      const int f0 = 8 * hv + 2 * ot;
      const f16x8 v0 = *(const f16x8*)(vfrm(pb, f0) + l * 16);
      oacc[ot] = MFMA32(pa0, v0, oacc[ot]);
      const f16x8 v1 = *(const f16x8*)(vfrm(pb, f0 + 1) + l * 16);
      oacc[ot] = MFMA32(pa1, v1, oacc[ot]);
    }
    __builtin_amdgcn_s_setprio(0);
  };

  stageK(0, 0);
  __syncthreads();                                // K(0) ready

  #pragma unroll 1
  for (int it = 0; it < 128; ++it) {
    const int cur = it & 1, prv = cur ^ 1;
    if (it < 127) stageK(prv, (it + 1) * 32);     // K(it+1), drained at barrier
    stageV(cur, it * 32);                         // V(it), read next iter

    const bool own = (hv == ((it + par) & 1));    // wave-uniform, desynced

    f32x16 s;
    if (own) {
      f32x16 sa, sb;
      #pragma unroll
      for (int i = 0; i < 16; ++i) { sa[i] = 0.0f; sb[i] = 0.0f; }
      __builtin_amdgcn_s_setprio(1);
      #pragma unroll
      for (int ks = 0; ks < 8; ++ks) {
        const f16x8 kf0 = *(const f16x8*)(kfrm(cur, ks) + l * 16);
        sa = MFMA32(kf0, qf[ks], sa);
        const f16x8 kf1 = *(const f16x8*)(kfrm(cur, ks + 8) + l * 16);
        sb = MFMA32(kf1, qf[ks + 8], sb);
      }
      __builtin_amdgcn_s_setprio(0);
      #pragma unroll
      for (int i = 0; i < 16; ++i) s[i] = sa[i] + sb[i];
    }

    if (it > 0) pvstep(prv);

    if (own) {
      __builtin_amdgcn_s_setprio(1);              // owner critical-path priority
      const float mprev = it ? MLm[ln] : -3e38f;
      const float lprev = it ? MLl[ln] : 0.0f;
      // max3 tree: 6 ops, depth 3 (fuses to v_max3_f32)
      const float t0 = f3(s[0], s[1], s[2]),  t1 = f3(s[3], s[4], s[5]);
      const float t2 = f3(s[6], s[7], s[8]),  t3 = f3(s[9], s[10], s[11]);
      const float t4 = f3(s[12], s[13], s[14]);
      float pmax = fmaxf(f3(t0, t1, t2), f3(t3, t4, s[15]));
      pmax = fmaxf(pmax, __shfl_xor(pmax, 32));
      const bool need = !__all(pmax - mprev <= 8.0f);   // defer-max (T13)
      const float mnew = need ? fmaxf(mprev, pmax) : mprev;
      float p[16];
      #pragma unroll
      for (int r = 0; r < 16; ++r) p[r] = __expf(s[r] - mnew);  // native v_exp path
      float sm8[8], sm4[4];
      #pragma unroll
      for (int i = 0; i < 8; ++i) sm8[i] = p[2 * i] + p[2 * i + 1];
      #pragma unroll
      for (int i = 0; i < 4; ++i) sm4[i] = sm8[2 * i] + sm8[2 * i + 1];
      float psum = (sm4[0] + sm4[1]) + (sm4[2] + sm4[3]);
      psum += __shfl_xor(psum, 32);
      float alpha = 1.0f, lnew;
      if (need) { alpha = __expf(mprev - mnew); lnew = lprev * alpha + psum; }
      else      { lnew = lprev + psum; }
      if (l < 32) {
        MLm[ln] = mnew;
        MLl[ln] = lnew;
        float* af = AFa(cur);
        af[ln] = alpha;
        if (ln == 0) af[32] = need ? 1.0f : 0.0f;
      }
      u32 pw[8];
      #pragma unroll
      for (int i = 0; i < 8; ++i) pw[i] = pk(p[2 * i], p[2 * i + 1]);
      plswap(pw[0], pw[2]); plswap(pw[1], pw[3]);
      plswap(pw[4], pw[6]); plswap(pw[5], pw[7]);
      *(u32x4*)(pfrm(cur, 0) + l * 16) = u32x4{pw[0], pw[1], pw[2], pw[3]};
      *(u32x4*)(pfrm(cur, 1) + l * 16) = u32x4{pw[4], pw[5], pw[6], pw[7]};
      __builtin_amdgcn_s_setprio(0);
    }
    __syncthreads();   // drains K(it+1)/V(it); publishes P/ML/AF(it)
  }

  // epilogue part 1: PV(127) (buffers pb=1), grab 1/l values
  pvstep(1);
  float invv[16];
  #pragma unroll
  for (int r = 0; r < 16; ++r)
    invv[r] = 1.0f / MLl[(r & 3) + 8 * (r >> 2) + 4 * lh];
  __syncthreads();                                // everyone done with K/ML regions

  // epilogue part 2: normalized O-tile -> LDS [64][264] f16
  f16* const OT = (f16*)SMEM;
  #pragma unroll
  for (int r = 0; r < 16; ++r) {
    const int q = (r & 3) + 8 * (r >> 2) + 4 * lh;
    const int qq = 32 * g + q;
    #pragma unroll
    for (int ot = 0; ot < 4; ++ot)
      OT[qq * 264 + 128 * hv + ot * 32 + ln] = (f16)(oacc[ot][r] * invv[r]);
  }
  __syncthreads();

  // epilogue part 3: fused out-projection (verified oproj body, bf from LDS)
  {
    const int lr = l & 15, lq = l >> 4;           // 16x4 lane split
    const f16* orow = OT + (w * 16 + lr) * 264;
    f32x4 acc[16];
    #pragma unroll
    for (int m = 0; m < 16; ++m) acc[m] = f32x4{0.f, 0.f, 0.f, 0.f};
    #pragma unroll
    for (int kk = 0; kk < 8; ++kk) {
      const f16x8 bf = *(const f16x8*)&orow[kk * 32 + lq * 8];
      #pragma unroll
      for (int m = 0; m < 16; ++m) {
        f16x8 af = *(const f16x8*)&Wo[(size_t)(m * 16 + lr) * CC + kk * 32 + lq * 8];
        acc[m] = MFMA(af, bf, acc[m]);
      }
    }
    #pragma unroll
    for (int m = 0; m < 16; ++m) {
      const int c = m * 16 + lq * 4;
      const float4 bv4 = *(const float4*)&bo[c];
      const size_t base = ((size_t)b * CC + c) * CN + q0 + w * 16 + lr;
      out[base + 0 * (size_t)CN] = acc[m][0] + bv4.x;
      out[base + 1 * (size_t)CN] = acc[m][1] + bv4.y;
      out[base + 2 * (size_t)CN] = acc[m][2] + bv4.z;
      out[base + 3 * (size_t)CN] = acc[m][3] + bv4.w;
    }
  }
}

extern "C" void kernel_launch(void* const* d_in, const int* in_sizes, int n_in,
                              void* d_out, int out_size, void* d_ws, size_t ws_size,
                              hipStream_t stream) {
  const float* x  = (const float*)d_in[0];
  const float* wq = (const float*)d_in[1];
  const float* bq = (const float*)d_in[2];
  const float* wk = (const float*)d_in[3];
  const float* bk = (const float*)d_in[4];
  const float* wv = (const float*)d_in[5];
  const float* bv = (const float*)d_in[6];
  const float* wo = (const float*)d_in[7];
  const float* bo = (const float*)d_in[8];

  f16* W  = (f16*)d_ws;                     // 4 x 65536 f16 weights
  f16* Qd = W + 262144;                     // [B,N,256]
  f16* Kd = Qd + (size_t)CB * CN * CC;      // [B,N,256]
  f16* Vt = Kd + (size_t)CB * CN * CC;      // [B,256,N]

  prep_weights<<<256, 256, 0, stream>>>(wq, wk, wv, wo, W);
  qkv_kernel<<<512, 128, 0, stream>>>(x, W, W + 65536, W + 131072, bq, bk, bv, Qd, Kd, Vt);
  attn_kernel<<<512, 256, 0, stream>>>(Qd, Kd, Vt, W + 196608, bo, (float*)d_out);
}